// Round 6
// baseline (338.754 us; speedup 1.0000x reference)
//
#include <hip/hip_runtime.h>
#include <hip/hip_bf16.h>

typedef unsigned short u16;
typedef unsigned int u32;
typedef __bf16 bf16x8 __attribute__((ext_vector_type(8)));
typedef float float4v __attribute__((ext_vector_type(4)));
typedef float f32x16 __attribute__((ext_vector_type(16)));
typedef u32 u32x4 __attribute__((ext_vector_type(4)));
typedef u16 u16x4 __attribute__((ext_vector_type(4)));
typedef u16 u16x8 __attribute__((ext_vector_type(8)));

__device__ __forceinline__ u16 f2b(float f) {
  u32 u = __float_as_uint(f);
  u += 0x7fffu + ((u >> 16) & 1u);
  return (u16)(u >> 16);
}

__device__ __forceinline__ void gload16(const void* g, void* l) {
  __builtin_amdgcn_global_load_lds(
      (const __attribute__((address_space(1))) void*)g,
      (__attribute__((address_space(3))) void*)l, 16, 0, 0);
}

// ------- weight transpose+convert: fp32 (R,C) -> bf16 (C,R) ---------------
__global__ __launch_bounds__(256) void transpose_kernel(
    const float* __restrict__ in, u16* __restrict__ out, int R, int C) {
  __shared__ float t[32][33];
  int c0 = blockIdx.x * 32, r0 = blockIdx.y * 32;
  for (int i = threadIdx.y; i < 32; i += 8)
    t[i][threadIdx.x] = in[(size_t)(r0 + i) * C + c0 + threadIdx.x];
  __syncthreads();
  for (int i = threadIdx.y; i < 32; i += 8)
    out[(size_t)(c0 + i) * R + r0 + threadIdx.x] = f2b(t[threadIdx.x][i]);
}

// ------- rel-pos bias: bias2[k] = dot(rpe[k+976], w) * log2(e) ------------
__global__ __launch_bounds__(256) void bias1d_kernel(
    const float* __restrict__ table, const float* __restrict__ w,
    float* __restrict__ out) {
  int i = blockIdx.x * 256 + threadIdx.x;
  if (i >= 2047) return;
  const float* row = table + (size_t)(i + 976) * 64;
  float s = 0.f;
#pragma unroll
  for (int d = 0; d < 64; ++d) s += row[d] * w[d];
  out[i] = s * 1.4426950408889634f;
}

// ------- LayerNorm: fp32 in -> bf16 out, one wave per row of 512 ----------
__global__ __launch_bounds__(256) void ln_kernel(
    const float* __restrict__ xr, const float* __restrict__ g,
    const float* __restrict__ bta, u16* __restrict__ out) {
  int row = blockIdx.x * 4 + (threadIdx.x >> 6);
  int lane = threadIdx.x & 63;
  const float* xp = xr + (size_t)row * 512 + lane * 8;
  float4v v0 = *reinterpret_cast<const float4v*>(xp);
  float4v v1 = *reinterpret_cast<const float4v*>(xp + 4);
  float s = v0[0] + v0[1] + v0[2] + v0[3] + v1[0] + v1[1] + v1[2] + v1[3];
  float q = v0[0]*v0[0] + v0[1]*v0[1] + v0[2]*v0[2] + v0[3]*v0[3]
          + v1[0]*v1[0] + v1[1]*v1[1] + v1[2]*v1[2] + v1[3]*v1[3];
#pragma unroll
  for (int d = 1; d < 64; d <<= 1) { s += __shfl_xor(s, d); q += __shfl_xor(q, d); }
  float mu = s * (1.f / 512.f);
  float var = q * (1.f / 512.f) - mu * mu;
  float rstd = rsqrtf(var + 1e-5f);
  const float* gp = g + lane * 8;
  const float* bp = bta + lane * 8;
  u16x8 o;
#pragma unroll
  for (int e = 0; e < 4; ++e) o[e] = f2b((v0[e] - mu) * rstd * gp[e] + bp[e]);
#pragma unroll
  for (int e = 0; e < 4; ++e) o[4 + e] = f2b((v1[e] - mu) * rstd * gp[4 + e] + bp[4 + e]);
  *reinterpret_cast<u16x8*>(out + (size_t)row * 512 + lane * 8) = o;
}

// ------- MFMA GEMM BM=128,BN=128 (m97 structure) --------------------------
template<int ACT, int RES, int OUTF>
__global__ __launch_bounds__(256) void gemm_kernel(
    const u16* __restrict__ A, const u16* __restrict__ Bt,
    const float* __restrict__ bias, const float* resid,
    void* outp, int M, int N, int K) {
  __shared__ u16 Al[128 * 32];
  __shared__ u16 Bl[128 * 32];
  const int tid = threadIdx.x;
  const int lane = tid & 63;
  const int w = tid >> 6;
  const int wr = w >> 1, wc = w & 1;
  const int lg = lane >> 4, lr = lane & 15;
  const int m0 = blockIdx.y * 128, n0 = blockIdx.x * 128;
  const int gcol = (lane & 3) * 8;

  float4v acc[4][4];
#pragma unroll
  for (int i = 0; i < 4; ++i)
#pragma unroll
    for (int j = 0; j < 4; ++j) acc[i][j] = {0.f, 0.f, 0.f, 0.f};

  const u16* Abase = A + (size_t)m0 * K;
  const u16* Bbase = Bt + (size_t)n0 * K;
  const int grow = lane >> 2;

  for (int kt = 0; kt < K; kt += 32) {
    __syncthreads();
#pragma unroll
    for (int c = 0; c < 2; ++c) {
      int r = w * 32 + c * 16 + grow;
      gload16(Abase + (size_t)r * K + kt + gcol, &Al[(w * 32 + c * 16) * 32]);
      gload16(Bbase + (size_t)r * K + kt + gcol, &Bl[(w * 32 + c * 16) * 32]);
    }
    __syncthreads();
    bf16x8 af[4], bg[4];
#pragma unroll
    for (int i = 0; i < 4; ++i)
      af[i] = *reinterpret_cast<const bf16x8*>(&Al[(wr * 64 + i * 16 + lr) * 32 + lg * 8]);
#pragma unroll
    for (int j = 0; j < 4; ++j)
      bg[j] = *reinterpret_cast<const bf16x8*>(&Bl[(wc * 64 + j * 16 + lr) * 32 + lg * 8]);
#pragma unroll
    for (int i = 0; i < 4; ++i)
#pragma unroll
      for (int j = 0; j < 4; ++j)
        acc[i][j] = __builtin_amdgcn_mfma_f32_16x16x32_bf16(af[i], bg[j], acc[i][j], 0, 0, 0);
  }

#pragma unroll
  for (int i = 0; i < 4; ++i) {
    int rbase = m0 + wr * 64 + i * 16 + lg * 4;
#pragma unroll
    for (int j = 0; j < 4; ++j) {
      int c = n0 + wc * 64 + j * 16 + lr;
      float bv = bias[c];
#pragma unroll
      for (int jj = 0; jj < 4; ++jj) {
        int rr = rbase + jj;
        float v = acc[i][j][jj] + bv;
        if (ACT == 1) v = 0.5f * v * (1.0f + erff(v * 0.70710678118654752f));
        if (RES) v += resid[(size_t)rr * N + c];
        if (OUTF)
          reinterpret_cast<float*>(outp)[(size_t)rr * N + c] = v;
        else
          reinterpret_cast<u16*>(outp)[(size_t)rr * N + c] = f2b(v);
      }
    }
  }
}

// ------- MFMA GEMM BM=64,BN=128 (for N=512 shapes: 2 blocks/CU) -----------
template<int ACT, int RES, int OUTF>
__global__ __launch_bounds__(256) void gemm64_kernel(
    const u16* __restrict__ A, const u16* __restrict__ Bt,
    const float* __restrict__ bias, const float* resid,
    void* outp, int M, int N, int K) {
  __shared__ u16 Al[64 * 32];
  __shared__ u16 Bl[128 * 32];
  const int tid = threadIdx.x;
  const int lane = tid & 63;
  const int w = tid >> 6;
  const int lg = lane >> 4, lr = lane & 15;
  const int m0 = blockIdx.y * 64, n0 = blockIdx.x * 128;
  const int grow = lane >> 2;
  const int gcol = (lane & 3) * 8;

  float4v acc[4][2];
#pragma unroll
  for (int i = 0; i < 4; ++i)
#pragma unroll
    for (int j = 0; j < 2; ++j) acc[i][j] = {0.f, 0.f, 0.f, 0.f};

  const u16* Abase = A + (size_t)m0 * K;
  const u16* Bbase = Bt + (size_t)n0 * K;

  for (int kt = 0; kt < K; kt += 32) {
    __syncthreads();
    gload16(Abase + (size_t)(w * 16 + grow) * K + kt + gcol, &Al[(w * 16) * 32]);
#pragma unroll
    for (int c = 0; c < 2; ++c)
      gload16(Bbase + (size_t)(w * 32 + c * 16 + grow) * K + kt + gcol,
              &Bl[(w * 32 + c * 16) * 32]);
    __syncthreads();
    bf16x8 af[4], bg[2];
#pragma unroll
    for (int i = 0; i < 4; ++i)
      af[i] = *reinterpret_cast<const bf16x8*>(&Al[(i * 16 + lr) * 32 + lg * 8]);
#pragma unroll
    for (int j = 0; j < 2; ++j)
      bg[j] = *reinterpret_cast<const bf16x8*>(&Bl[(w * 32 + j * 16 + lr) * 32 + lg * 8]);
#pragma unroll
    for (int i = 0; i < 4; ++i)
#pragma unroll
      for (int j = 0; j < 2; ++j)
        acc[i][j] = __builtin_amdgcn_mfma_f32_16x16x32_bf16(af[i], bg[j], acc[i][j], 0, 0, 0);
  }

#pragma unroll
  for (int i = 0; i < 4; ++i) {
    int rbase = m0 + i * 16 + lg * 4;
#pragma unroll
    for (int j = 0; j < 2; ++j) {
      int c = n0 + w * 32 + j * 16 + lr;
      float bv = bias[c];
#pragma unroll
      for (int jj = 0; jj < 4; ++jj) {
        int rr = rbase + jj;
        float v = acc[i][j][jj] + bv;
        if (ACT == 1) v = 0.5f * v * (1.0f + erff(v * 0.70710678118654752f));
        if (RES) v += resid[(size_t)rr * N + c];
        if (OUTF)
          reinterpret_cast<float*>(outp)[(size_t)rr * N + c] = v;
        else
          reinterpret_cast<u16*>(outp)[(size_t)rr * N + c] = f2b(v);
      }
    }
  }
}

// ------- fused flash attention, swapped-QK^T, pipelined -------------------
// qkv: (B,T,3,H,64) bf16, row stride 1536. out: (B,T,512) bf16.
// Round-5 winner (69.3 us) + serial-chain cuts. Occupancy is register-
// quantum-capped at 2 waves/SIMD (r1-r4 ledger), so the lever is the
// per-tile serial dependency chain:
//  - max and row-sum reductions tree-ified (depth 31 -> 5): ~200 cyc of
//    pure latency saved per tile per wave.
//  - BIASF=0 scale as whole-vector op (packed f32 muls).
//  - V-scatter as 4x ds_write_b64 (r5); s_setprio around MFMA clusters.
template<int BIASF>
__global__ __launch_bounds__(256) void attn_kernel(
    const u16* __restrict__ qkv, const float* __restrict__ bias2,
    u16* __restrict__ out) {
  __shared__ u16 Vt[2][64 * 64];  // [buf][dv][key], slot-swizzled
  const int tid = threadIdx.x;
  const int lane = tid & 63;
  const int w = tid >> 6;
  const int hl = lane >> 5;
  const int l31 = lane & 31;
  const int bh = blockIdx.y;
  const int b = bh >> 3, hh = bh & 7;
  const int q0 = blockIdx.x * 128;
  const int qr = q0 + w * 32 + l31;
  const u16* base = qkv + (size_t)b * 1024 * 1536 + hh * 64;
  const float SC = 0.18033688011112042f;  // 0.125 * log2(e)

  bf16x8 qb[4];
  {
    const u16* qp = base + (size_t)qr * 1536 + hl * 8;
#pragma unroll
    for (int dc = 0; dc < 4; ++dc)
      qb[dc] = *reinterpret_cast<const bf16x8*>(qp + dc * 16);
  }

  const int vk4 = (tid >> 4) * 4;   // key group of 4 this thread stages
  const int dv0 = (tid & 15) * 4;   // dv chunk of 4

  f32x16 oA = {}, oB = {};
  float mreg = -1e30f, lsum = 0.f;

  // ---- prologue: V tile 0 -> Vt[0]; K tile 0 -> regs ----
  u16x4 vrow[4];
  {
    const u16* vp = base + (size_t)vk4 * 1536 + 1024 + dv0;
#pragma unroll
    for (int j = 0; j < 4; ++j)
      vrow[j] = *reinterpret_cast<const u16x4*>(vp + j * 1536);
  }
  bf16x8 ka[4], kb[4];
  {
    const u16* kp = base + (size_t)l31 * 1536 + 512 + hl * 8;
#pragma unroll
    for (int dc = 0; dc < 4; ++dc) {
      ka[dc] = *reinterpret_cast<const bf16x8*>(kp + dc * 16);
      kb[dc] = *reinterpret_cast<const bf16x8*>(kp + 32 * 1536 + dc * 16);
    }
  }
  {
    char* vb = (char*)Vt[0];
#pragma unroll
    for (int e = 0; e < 4; ++e) {
      int dv = dv0 + e;
      u16x4 wv = {vrow[0][e], vrow[1][e], vrow[2][e], vrow[3][e]};
      *reinterpret_cast<u16x4*>(vb + dv * 128 +
          ((vk4 * 2) ^ (((dv + (dv >> 3)) & 7) << 4))) = wv;
    }
  }
  __syncthreads();

  for (int t = 0; t < 16; ++t) {
    const int kt = t * 64;
    const int cur = t & 1;

    // S^T = K·Q^T from registers
    f32x16 sA = {}, sB = {};
    __builtin_amdgcn_s_setprio(1);
#pragma unroll
    for (int dc = 0; dc < 4; ++dc) {
      sA = __builtin_amdgcn_mfma_f32_32x32x16_bf16(ka[dc], qb[dc], sA, 0, 0, 0);
      sB = __builtin_amdgcn_mfma_f32_32x32x16_bf16(kb[dc], qb[dc], sB, 0, 0, 0);
    }
    __builtin_amdgcn_s_setprio(0);
    // prefetch next K and V tiles (latency hides under softmax+PV)
    if (t < 15) {
      const u16* kp = base + (size_t)(kt + 64 + l31) * 1536 + 512 + hl * 8;
#pragma unroll
      for (int dc = 0; dc < 4; ++dc) {
        ka[dc] = *reinterpret_cast<const bf16x8*>(kp + dc * 16);
        kb[dc] = *reinterpret_cast<const bf16x8*>(kp + 32 * 1536 + dc * 16);
      }
      const u16* vp = base + (size_t)(kt + 64 + vk4) * 1536 + 1024 + dv0;
#pragma unroll
      for (int j = 0; j < 4; ++j)
        vrow[j] = *reinterpret_cast<const u16x4*>(vp + j * 1536);
    }

    // scale (+bias), exp2 domain
    if (BIASF) {
#pragma unroll
      for (int r = 0; r < 16; ++r) {
        int key = (r & 3) + 8 * (r >> 2) + 4 * hl;
        sA[r] = fmaf(sA[r], SC, bias2[qr - kt - key + 1023]);
        sB[r] = fmaf(sB[r], SC, bias2[qr - kt - 32 - key + 1023]);
      }
    } else {
      sA *= SC;
      sB *= SC;
    }

    // online softmax with defer-max (THR = 8*log2e); tree max (depth 5)
    float mv[16];
#pragma unroll
    for (int r = 0; r < 16; ++r) mv[r] = fmaxf(sA[r], sB[r]);
#pragma unroll
    for (int s = 8; s > 0; s >>= 1)
#pragma unroll
      for (int r = 0; r < s; ++r) mv[r] = fmaxf(mv[r], mv[r + s]);
    float mx = fmaxf(mv[0], __shfl_xor(mv[0], 32));
    if (!__all(mx - mreg <= 11.5416f)) {
      float mn = fmaxf(mreg, mx);
      float al = exp2f(mreg - mn);
      mreg = mn;
      lsum *= al;
      oA *= al;
      oB *= al;
    }
    float pv[16];
#pragma unroll
    for (int r = 0; r < 16; ++r) {
      float pa = exp2f(sA[r] - mreg);
      float pb = exp2f(sB[r] - mreg);
      sA[r] = pa; sB[r] = pb;
      pv[r] = pa + pb;
    }
#pragma unroll
    for (int s = 8; s > 0; s >>= 1)
#pragma unroll
      for (int r = 0; r < s; ++r) pv[r] += pv[r + s];
    lsum += pv[0];

    // pack P to bf16 and exchange halves -> B-frags
    u32 wa[8], wb[8], ra[8], rb[8];
#pragma unroll
    for (int i = 0; i < 8; ++i) {
      wa[i] = (__float_as_uint(sA[2 * i + 1]) & 0xFFFF0000u) |
              (__float_as_uint(sA[2 * i]) >> 16);
      wb[i] = (__float_as_uint(sB[2 * i + 1]) & 0xFFFF0000u) |
              (__float_as_uint(sB[2 * i]) >> 16);
    }
#pragma unroll
    for (int i = 0; i < 8; ++i) {
      ra[i] = (u32)__shfl_xor((int)wa[i], 32);
      rb[i] = (u32)__shfl_xor((int)wb[i], 32);
    }
    u32x4 f00 = {hl ? ra[2] : wa[0], hl ? ra[3] : wa[1],
                 hl ? wa[2] : ra[0], hl ? wa[3] : ra[1]};
    u32x4 f01 = {hl ? ra[6] : wa[4], hl ? ra[7] : wa[5],
                 hl ? wa[6] : ra[4], hl ? wa[7] : ra[5]};
    u32x4 f10 = {hl ? rb[2] : wb[0], hl ? rb[3] : wb[1],
                 hl ? wb[2] : rb[0], hl ? wb[3] : rb[1]};
    u32x4 f11 = {hl ? rb[6] : wb[4], hl ? rb[7] : wb[5],
                 hl ? wb[6] : rb[4], hl ? wb[7] : rb[5]};
    bf16x8 p00 = __builtin_bit_cast(bf16x8, f00);
    bf16x8 p01 = __builtin_bit_cast(bf16x8, f01);
    bf16x8 p10 = __builtin_bit_cast(bf16x8, f10);
    bf16x8 p11 = __builtin_bit_cast(bf16x8, f11);

    // O^T += V^T · P from Vt[cur]
    const char* vbc = (const char*)Vt[cur];
    const int sl0 = ((l31 + (l31 >> 3)) & 7) << 4;
    const int sl1 = (((32 + l31) + ((32 + l31) >> 3)) & 7) << 4;
    const char* vp0 = vbc + l31 * 128;
    const char* vp1 = vbc + (32 + l31) * 128;
    const int cb = hl * 16;
    bf16x8 va;
    __builtin_amdgcn_s_setprio(1);
    va = *reinterpret_cast<const bf16x8*>(vp0 + ((cb + 0) ^ sl0));
    oA = __builtin_amdgcn_mfma_f32_32x32x16_bf16(va, p00, oA, 0, 0, 0);
    va = *reinterpret_cast<const bf16x8*>(vp0 + ((cb + 32) ^ sl0));
    oA = __builtin_amdgcn_mfma_f32_32x32x16_bf16(va, p01, oA, 0, 0, 0);
    va = *reinterpret_cast<const bf16x8*>(vp0 + ((cb + 64) ^ sl0));
    oA = __builtin_amdgcn_mfma_f32_32x32x16_bf16(va, p10, oA, 0, 0, 0);
    va = *reinterpret_cast<const bf16x8*>(vp0 + ((cb + 96) ^ sl0));
    oA = __builtin_amdgcn_mfma_f32_32x32x16_bf16(va, p11, oA, 0, 0, 0);
    va = *reinterpret_cast<const bf16x8*>(vp1 + ((cb + 0) ^ sl1));
    oB = __builtin_amdgcn_mfma_f32_32x32x16_bf16(va, p00, oB, 0, 0, 0);
    va = *reinterpret_cast<const bf16x8*>(vp1 + ((cb + 32) ^ sl1));
    oB = __builtin_amdgcn_mfma_f32_32x32x16_bf16(va, p01, oB, 0, 0, 0);
    va = *reinterpret_cast<const bf16x8*>(vp1 + ((cb + 64) ^ sl1));
    oB = __builtin_amdgcn_mfma_f32_32x32x16_bf16(va, p10, oB, 0, 0, 0);
    va = *reinterpret_cast<const bf16x8*>(vp1 + ((cb + 96) ^ sl1));
    oB = __builtin_amdgcn_mfma_f32_32x32x16_bf16(va, p11, oB, 0, 0, 0);
    __builtin_amdgcn_s_setprio(0);

    // scatter next V tile into the other buffer (4x ds_write_b64)
    if (t < 15) {
      char* vb = (char*)Vt[cur ^ 1];
#pragma unroll
      for (int e = 0; e < 4; ++e) {
        int dv = dv0 + e;
        u16x4 wv = {vrow[0][e], vrow[1][e], vrow[2][e], vrow[3][e]};
        *reinterpret_cast<u16x4*>(vb + dv * 128 +
            ((vk4 * 2) ^ (((dv + (dv >> 3)) & 7) << 4))) = wv;
      }
    }
    __syncthreads();
  }

  lsum += __shfl_xor(lsum, 32);
  float inv = 1.f / lsum;
  size_t orow = (size_t)(b * 1024 + qr) * 512 + hh * 64;
#pragma unroll
  for (int g = 0; g < 4; ++g) {
    u16x4 pk;
#pragma unroll
    for (int e = 0; e < 4; ++e) pk[e] = f2b(oA[g * 4 + e] * inv);
    *reinterpret_cast<u16x4*>(out + orow + g * 8 + hl * 4) = pk;
#pragma unroll
    for (int e = 0; e < 4; ++e) pk[e] = f2b(oB[g * 4 + e] * inv);
    *reinterpret_cast<u16x4*>(out + orow + 32 + g * 8 + hl * 4) = pk;
  }
}

extern "C" void kernel_launch(void* const* d_in, const int* in_sizes, int n_in,
                              void* d_out, int out_size, void* d_ws, size_t ws_size,
                              hipStream_t stream) {
  (void)in_sizes; (void)n_in; (void)out_size; (void)ws_size;
  const float* x        = (const float*)d_in[0];
  const float* ns_g     = (const float*)d_in[2];
  const float* ns_b     = (const float*)d_in[3];
  const float* nt_g     = (const float*)d_in[4];
  const float* nt_b     = (const float*)d_in[5];
  const float* nf_g     = (const float*)d_in[6];
  const float* nf_b     = (const float*)d_in[7];
  const float* s_qkv_w  = (const float*)d_in[8];
  const float* s_qkv_b  = (const float*)d_in[9];
  const float* s_proj_w = (const float*)d_in[10];
  const float* s_proj_b = (const float*)d_in[11];
  const float* t_qkv_w  = (const float*)d_in[12];
  const float* t_qkv_b  = (const float*)d_in[13];
  const float* t_proj_w = (const float*)d_in[14];
  const float* t_proj_b = (const float*)d_in[15];
  const float* rpe_tab  = (const float*)d_in[16];
  const float* rpe_w    = (const float*)d_in[17];
  const float* ff_w1    = (const float*)d_in[18];
  const float* ff_b1    = (const float*)d_in[19];
  const float* ff_w2    = (const float*)d_in[20];
  const float* ff_b2    = (const float*)d_in[21];

  char* ws = (char*)d_ws;
  float* xr    = (float*)(ws);                 // 16.78 MB fp32 residual
  u16*   lnb   = (u16*)(ws + 16777216);        // 8.39 MB bf16 LN output
  u16*   big   = (u16*)(ws + 25165824);        // qkv bf16 / ffn hidden
  float* bias2 = (float*)(ws + 50331648);      // 8 KB (past qkv end; dead before ffn)
  u16*   wT    = (u16*)(ws + 58720256);        // 8.39 MB transposed bf16 weights
  u16* sqkvT  = wT;
  u16* tqkvT  = wT + 786432;
  u16* sprojT = wT + 1572864;
  u16* tprojT = wT + 1835008;
  u16* ff1T   = wT + 2097152;
  u16* ff2T   = wT + 3145728;
  u16* ao     = (u16*)d_out;     // attention output scratch
  float* outp = (float*)d_out;

  dim3 tb(32, 8);
  transpose_kernel<<<dim3(48, 16), tb, 0, stream>>>(s_qkv_w, sqkvT, 512, 1536);
  transpose_kernel<<<dim3(48, 16), tb, 0, stream>>>(t_qkv_w, tqkvT, 512, 1536);
  transpose_kernel<<<dim3(16, 16), tb, 0, stream>>>(s_proj_w, sprojT, 512, 512);
  transpose_kernel<<<dim3(16, 16), tb, 0, stream>>>(t_proj_w, tprojT, 512, 512);
  transpose_kernel<<<dim3(64, 16), tb, 0, stream>>>(ff_w1, ff1T, 512, 2048);
  transpose_kernel<<<dim3(16, 64), tb, 0, stream>>>(ff_w2, ff2T, 2048, 512);
  bias1d_kernel<<<8, 256, 0, stream>>>(rpe_tab, rpe_w, bias2);

  // --- spatial attention block ---
  ln_kernel<<<2048, 256, 0, stream>>>(x, ns_g, ns_b, lnb);
  gemm_kernel<0, 0, 0><<<dim3(12, 64), 256, 0, stream>>>(
      lnb, sqkvT, s_qkv_b, nullptr, big, 8192, 1536, 512);
  attn_kernel<0><<<dim3(8, 64), 256, 0, stream>>>(big, nullptr, ao);
  gemm64_kernel<0, 1, 1><<<dim3(4, 128), 256, 0, stream>>>(
      ao, sprojT, s_proj_b, x, xr, 8192, 512, 512);
  // --- temporal attention block ---
  ln_kernel<<<2048, 256, 0, stream>>>(xr, nt_g, nt_b, lnb);
  gemm_kernel<0, 0, 0><<<dim3(12, 64), 256, 0, stream>>>(
      lnb, tqkvT, t_qkv_b, nullptr, big, 8192, 1536, 512);
  attn_kernel<1><<<dim3(8, 64), 256, 0, stream>>>(big, bias2, ao);
  gemm64_kernel<0, 1, 1><<<dim3(4, 128), 256, 0, stream>>>(
      ao, tprojT, t_proj_b, xr, xr, 8192, 512, 512);
  // --- FFN block ---
  ln_kernel<<<2048, 256, 0, stream>>>(xr, nf_g, nf_b, lnb);
  gemm_kernel<1, 0, 0><<<dim3(16, 64), 256, 0, stream>>>(
      lnb, ff1T, ff_b1, nullptr, big, 8192, 2048, 512);
  gemm64_kernel<0, 1, 1><<<dim3(4, 128), 256, 0, stream>>>(
      big, ff2T, ff_b2, xr, outp, 8192, 512, 2048);
}

// Round 7
// 322.685 us; speedup vs baseline: 1.0498x; 1.0498x over previous
//
#include <hip/hip_runtime.h>
#include <hip/hip_bf16.h>

typedef unsigned short u16;
typedef unsigned int u32;
typedef __bf16 bf16x8 __attribute__((ext_vector_type(8)));
typedef float float4v __attribute__((ext_vector_type(4)));
typedef float f32x16 __attribute__((ext_vector_type(16)));
typedef u32 u32x4 __attribute__((ext_vector_type(4)));
typedef u16 u16x4 __attribute__((ext_vector_type(4)));
typedef u16 u16x8 __attribute__((ext_vector_type(8)));

__device__ __forceinline__ u16 f2b(float f) {
  u32 u = __float_as_uint(f);
  u += 0x7fffu + ((u >> 16) & 1u);
  return (u16)(u >> 16);
}

__device__ __forceinline__ void gload16(const void* g, void* l) {
  __builtin_amdgcn_global_load_lds(
      (const __attribute__((address_space(1))) void*)g,
      (__attribute__((address_space(3))) void*)l, 16, 0, 0);
}

// ------- weight transpose+convert: fp32 (R,C) -> bf16 (C,R) ---------------
__global__ __launch_bounds__(256) void transpose_kernel(
    const float* __restrict__ in, u16* __restrict__ out, int R, int C) {
  __shared__ float t[32][33];
  int c0 = blockIdx.x * 32, r0 = blockIdx.y * 32;
  for (int i = threadIdx.y; i < 32; i += 8)
    t[i][threadIdx.x] = in[(size_t)(r0 + i) * C + c0 + threadIdx.x];
  __syncthreads();
  for (int i = threadIdx.y; i < 32; i += 8)
    out[(size_t)(c0 + i) * R + r0 + threadIdx.x] = f2b(t[threadIdx.x][i]);
}

// ------- rel-pos bias: bias2[k] = dot(rpe[k+976], w) * log2(e) ------------
__global__ __launch_bounds__(256) void bias1d_kernel(
    const float* __restrict__ table, const float* __restrict__ w,
    float* __restrict__ out) {
  int i = blockIdx.x * 256 + threadIdx.x;
  if (i >= 2047) return;
  const float* row = table + (size_t)(i + 976) * 64;
  float s = 0.f;
#pragma unroll
  for (int d = 0; d < 64; ++d) s += row[d] * w[d];
  out[i] = s * 1.4426950408889634f;
}

// ------- LayerNorm: fp32 in -> bf16 out, one wave per row of 512 ----------
__global__ __launch_bounds__(256) void ln_kernel(
    const float* __restrict__ xr, const float* __restrict__ g,
    const float* __restrict__ bta, u16* __restrict__ out) {
  int row = blockIdx.x * 4 + (threadIdx.x >> 6);
  int lane = threadIdx.x & 63;
  const float* xp = xr + (size_t)row * 512 + lane * 8;
  float4v v0 = *reinterpret_cast<const float4v*>(xp);
  float4v v1 = *reinterpret_cast<const float4v*>(xp + 4);
  float s = v0[0] + v0[1] + v0[2] + v0[3] + v1[0] + v1[1] + v1[2] + v1[3];
  float q = v0[0]*v0[0] + v0[1]*v0[1] + v0[2]*v0[2] + v0[3]*v0[3]
          + v1[0]*v1[0] + v1[1]*v1[1] + v1[2]*v1[2] + v1[3]*v1[3];
#pragma unroll
  for (int d = 1; d < 64; d <<= 1) { s += __shfl_xor(s, d); q += __shfl_xor(q, d); }
  float mu = s * (1.f / 512.f);
  float var = q * (1.f / 512.f) - mu * mu;
  float rstd = rsqrtf(var + 1e-5f);
  const float* gp = g + lane * 8;
  const float* bp = bta + lane * 8;
  u16x8 o;
#pragma unroll
  for (int e = 0; e < 4; ++e) o[e] = f2b((v0[e] - mu) * rstd * gp[e] + bp[e]);
#pragma unroll
  for (int e = 0; e < 4; ++e) o[4 + e] = f2b((v1[e] - mu) * rstd * gp[4 + e] + bp[4 + e]);
  *reinterpret_cast<u16x8*>(out + (size_t)row * 512 + lane * 8) = o;
}

// ------- MFMA GEMM BM=128,BN=128 (m97 structure) --------------------------
template<int ACT, int RES, int OUTF>
__global__ __launch_bounds__(256) void gemm_kernel(
    const u16* __restrict__ A, const u16* __restrict__ Bt,
    const float* __restrict__ bias, const float* resid,
    void* outp, int M, int N, int K) {
  __shared__ u16 Al[128 * 32];
  __shared__ u16 Bl[128 * 32];
  const int tid = threadIdx.x;
  const int lane = tid & 63;
  const int w = tid >> 6;
  const int wr = w >> 1, wc = w & 1;
  const int lg = lane >> 4, lr = lane & 15;
  const int m0 = blockIdx.y * 128, n0 = blockIdx.x * 128;
  const int gcol = (lane & 3) * 8;

  float4v acc[4][4];
#pragma unroll
  for (int i = 0; i < 4; ++i)
#pragma unroll
    for (int j = 0; j < 4; ++j) acc[i][j] = {0.f, 0.f, 0.f, 0.f};

  const u16* Abase = A + (size_t)m0 * K;
  const u16* Bbase = Bt + (size_t)n0 * K;
  const int grow = lane >> 2;

  for (int kt = 0; kt < K; kt += 32) {
    __syncthreads();
#pragma unroll
    for (int c = 0; c < 2; ++c) {
      int r = w * 32 + c * 16 + grow;
      gload16(Abase + (size_t)r * K + kt + gcol, &Al[(w * 32 + c * 16) * 32]);
      gload16(Bbase + (size_t)r * K + kt + gcol, &Bl[(w * 32 + c * 16) * 32]);
    }
    __syncthreads();
    bf16x8 af[4], bg[4];
#pragma unroll
    for (int i = 0; i < 4; ++i)
      af[i] = *reinterpret_cast<const bf16x8*>(&Al[(wr * 64 + i * 16 + lr) * 32 + lg * 8]);
#pragma unroll
    for (int j = 0; j < 4; ++j)
      bg[j] = *reinterpret_cast<const bf16x8*>(&Bl[(wc * 64 + j * 16 + lr) * 32 + lg * 8]);
#pragma unroll
    for (int i = 0; i < 4; ++i)
#pragma unroll
      for (int j = 0; j < 4; ++j)
        acc[i][j] = __builtin_amdgcn_mfma_f32_16x16x32_bf16(af[i], bg[j], acc[i][j], 0, 0, 0);
  }

#pragma unroll
  for (int i = 0; i < 4; ++i) {
    int rbase = m0 + wr * 64 + i * 16 + lg * 4;
#pragma unroll
    for (int j = 0; j < 4; ++j) {
      int c = n0 + wc * 64 + j * 16 + lr;
      float bv = bias[c];
#pragma unroll
      for (int jj = 0; jj < 4; ++jj) {
        int rr = rbase + jj;
        float v = acc[i][j][jj] + bv;
        if (ACT == 1) v = 0.5f * v * (1.0f + erff(v * 0.70710678118654752f));
        if (RES) v += resid[(size_t)rr * N + c];
        if (OUTF)
          reinterpret_cast<float*>(outp)[(size_t)rr * N + c] = v;
        else
          reinterpret_cast<u16*>(outp)[(size_t)rr * N + c] = f2b(v);
      }
    }
  }
}

// ------- MFMA GEMM BM=64,BN=128 (for N=512 shapes: 2 blocks/CU) -----------
template<int ACT, int RES, int OUTF>
__global__ __launch_bounds__(256) void gemm64_kernel(
    const u16* __restrict__ A, const u16* __restrict__ Bt,
    const float* __restrict__ bias, const float* resid,
    void* outp, int M, int N, int K) {
  __shared__ u16 Al[64 * 32];
  __shared__ u16 Bl[128 * 32];
  const int tid = threadIdx.x;
  const int lane = tid & 63;
  const int w = tid >> 6;
  const int lg = lane >> 4, lr = lane & 15;
  const int m0 = blockIdx.y * 64, n0 = blockIdx.x * 128;
  const int grow = lane >> 2;
  const int gcol = (lane & 3) * 8;

  float4v acc[4][2];
#pragma unroll
  for (int i = 0; i < 4; ++i)
#pragma unroll
    for (int j = 0; j < 2; ++j) acc[i][j] = {0.f, 0.f, 0.f, 0.f};

  const u16* Abase = A + (size_t)m0 * K;
  const u16* Bbase = Bt + (size_t)n0 * K;

  for (int kt = 0; kt < K; kt += 32) {
    __syncthreads();
    gload16(Abase + (size_t)(w * 16 + grow) * K + kt + gcol, &Al[(w * 16) * 32]);
#pragma unroll
    for (int c = 0; c < 2; ++c)
      gload16(Bbase + (size_t)(w * 32 + c * 16 + grow) * K + kt + gcol,
              &Bl[(w * 32 + c * 16) * 32]);
    __syncthreads();
    bf16x8 af[4], bg[2];
#pragma unroll
    for (int i = 0; i < 4; ++i)
      af[i] = *reinterpret_cast<const bf16x8*>(&Al[(i * 16 + lr) * 32 + lg * 8]);
#pragma unroll
    for (int j = 0; j < 2; ++j)
      bg[j] = *reinterpret_cast<const bf16x8*>(&Bl[(w * 32 + j * 16 + lr) * 32 + lg * 8]);
#pragma unroll
    for (int i = 0; i < 4; ++i)
#pragma unroll
      for (int j = 0; j < 2; ++j)
        acc[i][j] = __builtin_amdgcn_mfma_f32_16x16x32_bf16(af[i], bg[j], acc[i][j], 0, 0, 0);
  }

#pragma unroll
  for (int i = 0; i < 4; ++i) {
    int rbase = m0 + i * 16 + lg * 4;
#pragma unroll
    for (int j = 0; j < 2; ++j) {
      int c = n0 + w * 32 + j * 16 + lr;
      float bv = bias[c];
#pragma unroll
      for (int jj = 0; jj < 4; ++jj) {
        int rr = rbase + jj;
        float v = acc[i][j][jj] + bv;
        if (ACT == 1) v = 0.5f * v * (1.0f + erff(v * 0.70710678118654752f));
        if (RES) v += resid[(size_t)rr * N + c];
        if (OUTF)
          reinterpret_cast<float*>(outp)[(size_t)rr * N + c] = v;
        else
          reinterpret_cast<u16*>(outp)[(size_t)rr * N + c] = f2b(v);
      }
    }
  }
}

// ------- fused flash attention, swapped-QK^T, pipelined -------------------
// qkv: (B,T,3,H,64) bf16, row stride 1536. out: (B,T,512) bf16.
// r5 winner (69.3 us) + VALU-count cut in the P pack/exchange. Occupancy is
// register-quantum-capped at 2 waves/SIMD (r1-r4 ledger); r6 showed the
// kernel is VALU-ISSUE-bound, not chain-latency-bound (tree reductions
// regressed), so the lever is fewer ops:
//  - P pack via v_cvt_pk_bf16_f32 (1 op / 2 floats, RNE) instead of 3
//    bit-ops per word: 48 -> 16 ops.
//  - half-exchange via v_permlane32_swap_b32 (VALU pipe) instead of
//    16 shfl + 16 cndmask selects: 32 -> 8 ops.
//  - V-scatter as 4x ds_write_b64; s_setprio around MFMA clusters (r5).
template<int BIASF>
__global__ __launch_bounds__(256) void attn_kernel(
    const u16* __restrict__ qkv, const float* __restrict__ bias2,
    u16* __restrict__ out) {
  __shared__ u16 Vt[2][64 * 64];  // [buf][dv][key], slot-swizzled
  const int tid = threadIdx.x;
  const int lane = tid & 63;
  const int w = tid >> 6;
  const int hl = lane >> 5;
  const int l31 = lane & 31;
  const int bh = blockIdx.y;
  const int b = bh >> 3, hh = bh & 7;
  const int q0 = blockIdx.x * 128;
  const int qr = q0 + w * 32 + l31;
  const u16* base = qkv + (size_t)b * 1024 * 1536 + hh * 64;
  const float SC = 0.18033688011112042f;  // 0.125 * log2(e)

  bf16x8 qb[4];
  {
    const u16* qp = base + (size_t)qr * 1536 + hl * 8;
#pragma unroll
    for (int dc = 0; dc < 4; ++dc)
      qb[dc] = *reinterpret_cast<const bf16x8*>(qp + dc * 16);
  }

  const int vk4 = (tid >> 4) * 4;   // key group of 4 this thread stages
  const int dv0 = (tid & 15) * 4;   // dv chunk of 4

  f32x16 oA = {}, oB = {};
  float mreg = -1e30f, lsum = 0.f;

  // ---- prologue: V tile 0 -> Vt[0]; K tile 0 -> regs ----
  u16x4 vrow[4];
  {
    const u16* vp = base + (size_t)vk4 * 1536 + 1024 + dv0;
#pragma unroll
    for (int j = 0; j < 4; ++j)
      vrow[j] = *reinterpret_cast<const u16x4*>(vp + j * 1536);
  }
  bf16x8 ka[4], kb[4];
  {
    const u16* kp = base + (size_t)l31 * 1536 + 512 + hl * 8;
#pragma unroll
    for (int dc = 0; dc < 4; ++dc) {
      ka[dc] = *reinterpret_cast<const bf16x8*>(kp + dc * 16);
      kb[dc] = *reinterpret_cast<const bf16x8*>(kp + 32 * 1536 + dc * 16);
    }
  }
  {
    char* vb = (char*)Vt[0];
#pragma unroll
    for (int e = 0; e < 4; ++e) {
      int dv = dv0 + e;
      u16x4 wv = {vrow[0][e], vrow[1][e], vrow[2][e], vrow[3][e]};
      *reinterpret_cast<u16x4*>(vb + dv * 128 +
          ((vk4 * 2) ^ (((dv + (dv >> 3)) & 7) << 4))) = wv;
    }
  }
  __syncthreads();

  for (int t = 0; t < 16; ++t) {
    const int kt = t * 64;
    const int cur = t & 1;

    // S^T = K·Q^T from registers
    f32x16 sA = {}, sB = {};
    __builtin_amdgcn_s_setprio(1);
#pragma unroll
    for (int dc = 0; dc < 4; ++dc) {
      sA = __builtin_amdgcn_mfma_f32_32x32x16_bf16(ka[dc], qb[dc], sA, 0, 0, 0);
      sB = __builtin_amdgcn_mfma_f32_32x32x16_bf16(kb[dc], qb[dc], sB, 0, 0, 0);
    }
    __builtin_amdgcn_s_setprio(0);
    // prefetch next K and V tiles (latency hides under softmax+PV)
    if (t < 15) {
      const u16* kp = base + (size_t)(kt + 64 + l31) * 1536 + 512 + hl * 8;
#pragma unroll
      for (int dc = 0; dc < 4; ++dc) {
        ka[dc] = *reinterpret_cast<const bf16x8*>(kp + dc * 16);
        kb[dc] = *reinterpret_cast<const bf16x8*>(kp + 32 * 1536 + dc * 16);
      }
      const u16* vp = base + (size_t)(kt + 64 + vk4) * 1536 + 1024 + dv0;
#pragma unroll
      for (int j = 0; j < 4; ++j)
        vrow[j] = *reinterpret_cast<const u16x4*>(vp + j * 1536);
    }

    // scale (+bias), exp2 domain
#pragma unroll
    for (int r = 0; r < 16; ++r) {
      int key = (r & 3) + 8 * (r >> 2) + 4 * hl;
      if (BIASF) {
        sA[r] = fmaf(sA[r], SC, bias2[qr - kt - key + 1023]);
        sB[r] = fmaf(sB[r], SC, bias2[qr - kt - 32 - key + 1023]);
      } else {
        sA[r] *= SC;
        sB[r] *= SC;
      }
    }

    // online softmax with defer-max (THR = 8*log2e)
    float mx = fmaxf(sA[0], sB[0]);
#pragma unroll
    for (int r = 1; r < 16; ++r) mx = fmaxf(mx, fmaxf(sA[r], sB[r]));
    mx = fmaxf(mx, __shfl_xor(mx, 32));
    if (!__all(mx - mreg <= 11.5416f)) {
      float mn = fmaxf(mreg, mx);
      float al = exp2f(mreg - mn);
      mreg = mn;
      lsum *= al;
      oA *= al;
      oB *= al;
    }
    float ps = 0.f;
#pragma unroll
    for (int r = 0; r < 16; ++r) {
      float pa = exp2f(sA[r] - mreg);
      float pb = exp2f(sB[r] - mreg);
      sA[r] = pa; sB[r] = pb;
      ps += pa + pb;
    }
    lsum += ps;

    // pack P to bf16 (v_cvt_pk_bf16_f32, RNE) and exchange halves via
    // v_permlane32_swap_b32: after swap(wa0,wa2), wa0 = {lo:wa0, hi:wa2.lo}
    // and wa2 = {lo:wa0.hi, hi:wa2} -- exactly the old hl-select of
    // {wa, shfl_xor(wa,32)} pairs. 80 ops -> 24 ops per tile.
    u32 wa[8], wb[8];
#pragma unroll
    for (int i = 0; i < 8; ++i) {
      asm("v_cvt_pk_bf16_f32 %0, %1, %2"
          : "=v"(wa[i]) : "v"(sA[2 * i]), "v"(sA[2 * i + 1]));
      asm("v_cvt_pk_bf16_f32 %0, %1, %2"
          : "=v"(wb[i]) : "v"(sB[2 * i]), "v"(sB[2 * i + 1]));
    }
#pragma unroll
    for (int i = 0; i < 2; ++i) {
      asm("v_permlane32_swap_b32 %0, %1" : "+v"(wa[i]), "+v"(wa[i + 2]));
      asm("v_permlane32_swap_b32 %0, %1" : "+v"(wa[i + 4]), "+v"(wa[i + 6]));
      asm("v_permlane32_swap_b32 %0, %1" : "+v"(wb[i]), "+v"(wb[i + 2]));
      asm("v_permlane32_swap_b32 %0, %1" : "+v"(wb[i + 4]), "+v"(wb[i + 6]));
    }
    u32x4 f00 = {wa[0], wa[1], wa[2], wa[3]};
    u32x4 f01 = {wa[4], wa[5], wa[6], wa[7]};
    u32x4 f10 = {wb[0], wb[1], wb[2], wb[3]};
    u32x4 f11 = {wb[4], wb[5], wb[6], wb[7]};
    bf16x8 p00 = __builtin_bit_cast(bf16x8, f00);
    bf16x8 p01 = __builtin_bit_cast(bf16x8, f01);
    bf16x8 p10 = __builtin_bit_cast(bf16x8, f10);
    bf16x8 p11 = __builtin_bit_cast(bf16x8, f11);

    // O^T += V^T · P from Vt[cur]
    const char* vbc = (const char*)Vt[cur];
    const int sl0 = ((l31 + (l31 >> 3)) & 7) << 4;
    const int sl1 = (((32 + l31) + ((32 + l31) >> 3)) & 7) << 4;
    const char* vp0 = vbc + l31 * 128;
    const char* vp1 = vbc + (32 + l31) * 128;
    const int cb = hl * 16;
    bf16x8 va;
    __builtin_amdgcn_s_setprio(1);
    va = *reinterpret_cast<const bf16x8*>(vp0 + ((cb + 0) ^ sl0));
    oA = __builtin_amdgcn_mfma_f32_32x32x16_bf16(va, p00, oA, 0, 0, 0);
    va = *reinterpret_cast<const bf16x8*>(vp0 + ((cb + 32) ^ sl0));
    oA = __builtin_amdgcn_mfma_f32_32x32x16_bf16(va, p01, oA, 0, 0, 0);
    va = *reinterpret_cast<const bf16x8*>(vp0 + ((cb + 64) ^ sl0));
    oA = __builtin_amdgcn_mfma_f32_32x32x16_bf16(va, p10, oA, 0, 0, 0);
    va = *reinterpret_cast<const bf16x8*>(vp0 + ((cb + 96) ^ sl0));
    oA = __builtin_amdgcn_mfma_f32_32x32x16_bf16(va, p11, oA, 0, 0, 0);
    va = *reinterpret_cast<const bf16x8*>(vp1 + ((cb + 0) ^ sl1));
    oB = __builtin_amdgcn_mfma_f32_32x32x16_bf16(va, p00, oB, 0, 0, 0);
    va = *reinterpret_cast<const bf16x8*>(vp1 + ((cb + 32) ^ sl1));
    oB = __builtin_amdgcn_mfma_f32_32x32x16_bf16(va, p01, oB, 0, 0, 0);
    va = *reinterpret_cast<const bf16x8*>(vp1 + ((cb + 64) ^ sl1));
    oB = __builtin_amdgcn_mfma_f32_32x32x16_bf16(va, p10, oB, 0, 0, 0);
    va = *reinterpret_cast<const bf16x8*>(vp1 + ((cb + 96) ^ sl1));
    oB = __builtin_amdgcn_mfma_f32_32x32x16_bf16(va, p11, oB, 0, 0, 0);
    __builtin_amdgcn_s_setprio(0);

    // scatter next V tile into the other buffer (4x ds_write_b64)
    if (t < 15) {
      char* vb = (char*)Vt[cur ^ 1];
#pragma unroll
      for (int e = 0; e < 4; ++e) {
        int dv = dv0 + e;
        u16x4 wv = {vrow[0][e], vrow[1][e], vrow[2][e], vrow[3][e]};
        *reinterpret_cast<u16x4*>(vb + dv * 128 +
            ((vk4 * 2) ^ (((dv + (dv >> 3)) & 7) << 4))) = wv;
      }
    }
    __syncthreads();
  }

  lsum += __shfl_xor(lsum, 32);
  float inv = 1.f / lsum;
  size_t orow = (size_t)(b * 1024 + qr) * 512 + hh * 64;
#pragma unroll
  for (int g = 0; g < 4; ++g) {
    u16x4 pk;
#pragma unroll
    for (int e = 0; e < 4; ++e) pk[e] = f2b(oA[g * 4 + e] * inv);
    *reinterpret_cast<u16x4*>(out + orow + g * 8 + hl * 4) = pk;
#pragma unroll
    for (int e = 0; e < 4; ++e) pk[e] = f2b(oB[g * 4 + e] * inv);
    *reinterpret_cast<u16x4*>(out + orow + 32 + g * 8 + hl * 4) = pk;
  }
}

extern "C" void kernel_launch(void* const* d_in, const int* in_sizes, int n_in,
                              void* d_out, int out_size, void* d_ws, size_t ws_size,
                              hipStream_t stream) {
  (void)in_sizes; (void)n_in; (void)out_size; (void)ws_size;
  const float* x        = (const float*)d_in[0];
  const float* ns_g     = (const float*)d_in[2];
  const float* ns_b     = (const float*)d_in[3];
  const float* nt_g     = (const float*)d_in[4];
  const float* nt_b     = (const float*)d_in[5];
  const float* nf_g     = (const float*)d_in[6];
  const float* nf_b     = (const float*)d_in[7];
  const float* s_qkv_w  = (const float*)d_in[8];
  const float* s_qkv_b  = (const float*)d_in[9];
  const float* s_proj_w = (const float*)d_in[10];
  const float* s_proj_b = (const float*)d_in[11];
  const float* t_qkv_w  = (const float*)d_in[12];
  const float* t_qkv_b  = (const float*)d_in[13];
  const float* t_proj_w = (const float*)d_in[14];
  const float* t_proj_b = (const float*)d_in[15];
  const float* rpe_tab  = (const float*)d_in[16];
  const float* rpe_w    = (const float*)d_in[17];
  const float* ff_w1    = (const float*)d_in[18];
  const float* ff_b1    = (const float*)d_in[19];
  const float* ff_w2    = (const float*)d_in[20];
  const float* ff_b2    = (const float*)d_in[21];

  char* ws = (char*)d_ws;
  float* xr    = (float*)(ws);                 // 16.78 MB fp32 residual
  u16*   lnb   = (u16*)(ws + 16777216);        // 8.39 MB bf16 LN output
  u16*   big   = (u16*)(ws + 25165824);        // qkv bf16 / ffn hidden
  float* bias2 = (float*)(ws + 50331648);      // 8 KB (past qkv end; dead before ffn)
  u16*   wT    = (u16*)(ws + 58720256);        // 8.39 MB transposed bf16 weights
  u16* sqkvT  = wT;
  u16* tqkvT  = wT + 786432;
  u16* sprojT = wT + 1572864;
  u16* tprojT = wT + 1835008;
  u16* ff1T   = wT + 2097152;
  u16* ff2T   = wT + 3145728;
  u16* ao     = (u16*)d_out;     // attention output scratch
  float* outp = (float*)d_out;

  dim3 tb(32, 8);
  transpose_kernel<<<dim3(48, 16), tb, 0, stream>>>(s_qkv_w, sqkvT, 512, 1536);
  transpose_kernel<<<dim3(48, 16), tb, 0, stream>>>(t_qkv_w, tqkvT, 512, 1536);
  transpose_kernel<<<dim3(16, 16), tb, 0, stream>>>(s_proj_w, sprojT, 512, 512);
  transpose_kernel<<<dim3(16, 16), tb, 0, stream>>>(t_proj_w, tprojT, 512, 512);
  transpose_kernel<<<dim3(64, 16), tb, 0, stream>>>(ff_w1, ff1T, 512, 2048);
  transpose_kernel<<<dim3(16, 64), tb, 0, stream>>>(ff_w2, ff2T, 2048, 512);
  bias1d_kernel<<<8, 256, 0, stream>>>(rpe_tab, rpe_w, bias2);

  // --- spatial attention block ---
  ln_kernel<<<2048, 256, 0, stream>>>(x, ns_g, ns_b, lnb);
  gemm_kernel<0, 0, 0><<<dim3(12, 64), 256, 0, stream>>>(
      lnb, sqkvT, s_qkv_b, nullptr, big, 8192, 1536, 512);
  attn_kernel<0><<<dim3(8, 64), 256, 0, stream>>>(big, nullptr, ao);
  gemm64_kernel<0, 1, 1><<<dim3(4, 128), 256, 0, stream>>>(
      ao, sprojT, s_proj_b, x, xr, 8192, 512, 512);
  // --- temporal attention block ---
  ln_kernel<<<2048, 256, 0, stream>>>(xr, nt_g, nt_b, lnb);
  gemm_kernel<0, 0, 0><<<dim3(12, 64), 256, 0, stream>>>(
      lnb, tqkvT, t_qkv_b, nullptr, big, 8192, 1536, 512);
  attn_kernel<1><<<dim3(8, 64), 256, 0, stream>>>(big, bias2, ao);
  gemm64_kernel<0, 1, 1><<<dim3(4, 128), 256, 0, stream>>>(
      ao, tprojT, t_proj_b, xr, xr, 8192, 512, 512);
  // --- FFN block ---
  ln_kernel<<<2048, 256, 0, stream>>>(xr, nf_g, nf_b, lnb);
  gemm_kernel<1, 0, 0><<<dim3(16, 64), 256, 0, stream>>>(
      lnb, ff1T, ff_b1, nullptr, big, 8192, 2048, 512);
  gemm64_kernel<0, 1, 1><<<dim3(4, 128), 256, 0, stream>>>(
      big, ff2T, ff_b2, xr, outp, 8192, 512, 2048);
}

// Round 8
// 305.653 us; speedup vs baseline: 1.1083x; 1.0557x over previous
//
#include <hip/hip_runtime.h>
#include <hip/hip_bf16.h>

typedef unsigned short u16;
typedef unsigned int u32;
typedef __bf16 bf16x8 __attribute__((ext_vector_type(8)));
typedef float float4v __attribute__((ext_vector_type(4)));
typedef float f32x16 __attribute__((ext_vector_type(16)));
typedef u32 u32x4 __attribute__((ext_vector_type(4)));
typedef u16 u16x4 __attribute__((ext_vector_type(4)));
typedef u16 u16x8 __attribute__((ext_vector_type(8)));

__device__ __forceinline__ u16 f2b(float f) {
  u32 u = __float_as_uint(f);
  u += 0x7fffu + ((u >> 16) & 1u);
  return (u16)(u >> 16);
}

__device__ __forceinline__ void gload16(const void* g, void* l) {
  __builtin_amdgcn_global_load_lds(
      (const __attribute__((address_space(1))) void*)g,
      (__attribute__((address_space(3))) void*)l, 16, 0, 0);
}

// ------- fused prep: 6 weight transposes + rel-pos bias + spatial LN ------
// One dispatch replaces 8 small serialized launches (r7 theory: launch
// overhead + 1-block/CU grids). Block-id ranges:
//   [0,2048)    spatial LayerNorm (4 rows/block of 8192)
//   [2048,2816) s_qkv_w  (512,1536) -> bf16 (1536,512)
//   [2816,3584) t_qkv_w  (512,1536)
//   [3584,3840) s_proj_w (512,512)
//   [3840,4096) t_proj_w (512,512)
//   [4096,5120) ff_w1    (512,2048)
//   [5120,6144) ff_w2    (2048,512)
//   [6144,6152) bias2[k] = dot(rpe[k+976], w) * log2(e)
__global__ __launch_bounds__(256) void prep_kernel(
    const float* __restrict__ x, const float* __restrict__ ns_g,
    const float* __restrict__ ns_b, u16* __restrict__ lnb,
    const float* __restrict__ sqkvW, u16* __restrict__ sqkvT,
    const float* __restrict__ tqkvW, u16* __restrict__ tqkvT,
    const float* __restrict__ sprojW, u16* __restrict__ sprojT,
    const float* __restrict__ tprojW, u16* __restrict__ tprojT,
    const float* __restrict__ ff1W, u16* __restrict__ ff1T,
    const float* __restrict__ ff2W, u16* __restrict__ ff2T,
    const float* __restrict__ rpe_tab, const float* __restrict__ rpe_w,
    float* __restrict__ bias2) {
  __shared__ float t[32][33];
  const int bid = blockIdx.x;
  const int tid = threadIdx.x;

  if (bid < 2048) {  // ---- spatial LayerNorm ----
    int row = bid * 4 + (tid >> 6);
    int lane = tid & 63;
    const float* xp = x + (size_t)row * 512 + lane * 8;
    float4v v0 = *reinterpret_cast<const float4v*>(xp);
    float4v v1 = *reinterpret_cast<const float4v*>(xp + 4);
    float s = v0[0] + v0[1] + v0[2] + v0[3] + v1[0] + v1[1] + v1[2] + v1[3];
    float q = v0[0]*v0[0] + v0[1]*v0[1] + v0[2]*v0[2] + v0[3]*v0[3]
            + v1[0]*v1[0] + v1[1]*v1[1] + v1[2]*v1[2] + v1[3]*v1[3];
#pragma unroll
    for (int d = 1; d < 64; d <<= 1) { s += __shfl_xor(s, d); q += __shfl_xor(q, d); }
    float mu = s * (1.f / 512.f);
    float var = q * (1.f / 512.f) - mu * mu;
    float rstd = rsqrtf(var + 1e-5f);
    const float* gp = ns_g + lane * 8;
    const float* bp = ns_b + lane * 8;
    u16x8 o;
#pragma unroll
    for (int e = 0; e < 4; ++e) o[e] = f2b((v0[e] - mu) * rstd * gp[e] + bp[e]);
#pragma unroll
    for (int e = 0; e < 4; ++e) o[4 + e] = f2b((v1[e] - mu) * rstd * gp[4 + e] + bp[4 + e]);
    *reinterpret_cast<u16x8*>(lnb + (size_t)row * 512 + lane * 8) = o;
    return;
  }
  if (bid >= 6144) {  // ---- rel-pos bias ----
    int i = (bid - 6144) * 256 + tid;
    if (i >= 2047) return;
    const float* row = rpe_tab + (size_t)(i + 976) * 64;
    float s = 0.f;
#pragma unroll
    for (int d = 0; d < 64; ++d) s += row[d] * rpe_w[d];
    bias2[i] = s * 1.4426950408889634f;
    return;
  }
  // ---- weight transpose+convert ----
  const float* tin; u16* tout; int R, C, w, tilesx;
  if (bid < 2816)      { tin = sqkvW;  tout = sqkvT;  R = 512;  C = 1536; w = bid - 2048; tilesx = 48; }
  else if (bid < 3584) { tin = tqkvW;  tout = tqkvT;  R = 512;  C = 1536; w = bid - 2816; tilesx = 48; }
  else if (bid < 3840) { tin = sprojW; tout = sprojT; R = 512;  C = 512;  w = bid - 3584; tilesx = 16; }
  else if (bid < 4096) { tin = tprojW; tout = tprojT; R = 512;  C = 512;  w = bid - 3840; tilesx = 16; }
  else if (bid < 5120) { tin = ff1W;   tout = ff1T;   R = 512;  C = 2048; w = bid - 4096; tilesx = 64; }
  else                 { tin = ff2W;   tout = ff2T;   R = 2048; C = 512;  w = bid - 5120; tilesx = 16; }
  int c0 = (w % tilesx) * 32, r0 = (w / tilesx) * 32;
  int tx = tid & 31, ty = tid >> 5;
  for (int i = ty; i < 32; i += 8)
    t[i][tx] = tin[(size_t)(r0 + i) * C + c0 + tx];
  __syncthreads();
  for (int i = ty; i < 32; i += 8)
    tout[(size_t)(c0 + i) * R + r0 + tx] = f2b(t[tx][i]);
}

// ------- LayerNorm: fp32 in -> bf16 out, one wave per row of 512 ----------
__global__ __launch_bounds__(256) void ln_kernel(
    const float* __restrict__ xr, const float* __restrict__ g,
    const float* __restrict__ bta, u16* __restrict__ out) {
  int row = blockIdx.x * 4 + (threadIdx.x >> 6);
  int lane = threadIdx.x & 63;
  const float* xp = xr + (size_t)row * 512 + lane * 8;
  float4v v0 = *reinterpret_cast<const float4v*>(xp);
  float4v v1 = *reinterpret_cast<const float4v*>(xp + 4);
  float s = v0[0] + v0[1] + v0[2] + v0[3] + v1[0] + v1[1] + v1[2] + v1[3];
  float q = v0[0]*v0[0] + v0[1]*v0[1] + v0[2]*v0[2] + v0[3]*v0[3]
          + v1[0]*v1[0] + v1[1]*v1[1] + v1[2]*v1[2] + v1[3]*v1[3];
#pragma unroll
  for (int d = 1; d < 64; d <<= 1) { s += __shfl_xor(s, d); q += __shfl_xor(q, d); }
  float mu = s * (1.f / 512.f);
  float var = q * (1.f / 512.f) - mu * mu;
  float rstd = rsqrtf(var + 1e-5f);
  const float* gp = g + lane * 8;
  const float* bp = bta + lane * 8;
  u16x8 o;
#pragma unroll
  for (int e = 0; e < 4; ++e) o[e] = f2b((v0[e] - mu) * rstd * gp[e] + bp[e]);
#pragma unroll
  for (int e = 0; e < 4; ++e) o[4 + e] = f2b((v1[e] - mu) * rstd * gp[4 + e] + bp[4 + e]);
  *reinterpret_cast<u16x8*>(out + (size_t)row * 512 + lane * 8) = o;
}

// ------- MFMA GEMM BM=128,BN=128 (m97 structure) --------------------------
template<int ACT, int RES, int OUTF>
__global__ __launch_bounds__(256) void gemm_kernel(
    const u16* __restrict__ A, const u16* __restrict__ Bt,
    const float* __restrict__ bias, const float* resid,
    void* outp, int M, int N, int K) {
  __shared__ u16 Al[128 * 32];
  __shared__ u16 Bl[128 * 32];
  const int tid = threadIdx.x;
  const int lane = tid & 63;
  const int w = tid >> 6;
  const int wr = w >> 1, wc = w & 1;
  const int lg = lane >> 4, lr = lane & 15;
  const int m0 = blockIdx.y * 128, n0 = blockIdx.x * 128;
  const int gcol = (lane & 3) * 8;

  float4v acc[4][4];
#pragma unroll
  for (int i = 0; i < 4; ++i)
#pragma unroll
    for (int j = 0; j < 4; ++j) acc[i][j] = {0.f, 0.f, 0.f, 0.f};

  const u16* Abase = A + (size_t)m0 * K;
  const u16* Bbase = Bt + (size_t)n0 * K;
  const int grow = lane >> 2;

  for (int kt = 0; kt < K; kt += 32) {
    __syncthreads();
#pragma unroll
    for (int c = 0; c < 2; ++c) {
      int r = w * 32 + c * 16 + grow;
      gload16(Abase + (size_t)r * K + kt + gcol, &Al[(w * 32 + c * 16) * 32]);
      gload16(Bbase + (size_t)r * K + kt + gcol, &Bl[(w * 32 + c * 16) * 32]);
    }
    __syncthreads();
    bf16x8 af[4], bg[4];
#pragma unroll
    for (int i = 0; i < 4; ++i)
      af[i] = *reinterpret_cast<const bf16x8*>(&Al[(wr * 64 + i * 16 + lr) * 32 + lg * 8]);
#pragma unroll
    for (int j = 0; j < 4; ++j)
      bg[j] = *reinterpret_cast<const bf16x8*>(&Bl[(wc * 64 + j * 16 + lr) * 32 + lg * 8]);
#pragma unroll
    for (int i = 0; i < 4; ++i)
#pragma unroll
      for (int j = 0; j < 4; ++j)
        acc[i][j] = __builtin_amdgcn_mfma_f32_16x16x32_bf16(af[i], bg[j], acc[i][j], 0, 0, 0);
  }

#pragma unroll
  for (int i = 0; i < 4; ++i) {
    int rbase = m0 + wr * 64 + i * 16 + lg * 4;
#pragma unroll
    for (int j = 0; j < 4; ++j) {
      int c = n0 + wc * 64 + j * 16 + lr;
      float bv = bias[c];
#pragma unroll
      for (int jj = 0; jj < 4; ++jj) {
        int rr = rbase + jj;
        float v = acc[i][j][jj] + bv;
        if (ACT == 1) v = 0.5f * v * (1.0f + erff(v * 0.70710678118654752f));
        if (RES) v += resid[(size_t)rr * N + c];
        if (OUTF)
          reinterpret_cast<float*>(outp)[(size_t)rr * N + c] = v;
        else
          reinterpret_cast<u16*>(outp)[(size_t)rr * N + c] = f2b(v);
      }
    }
  }
}

// ------- MFMA GEMM BM=64,BN=128 (for N=512 shapes: 2 blocks/CU) -----------
template<int ACT, int RES, int OUTF>
__global__ __launch_bounds__(256) void gemm64_kernel(
    const u16* __restrict__ A, const u16* __restrict__ Bt,
    const float* __restrict__ bias, const float* resid,
    void* outp, int M, int N, int K) {
  __shared__ u16 Al[64 * 32];
  __shared__ u16 Bl[128 * 32];
  const int tid = threadIdx.x;
  const int lane = tid & 63;
  const int w = tid >> 6;
  const int lg = lane >> 4, lr = lane & 15;
  const int m0 = blockIdx.y * 64, n0 = blockIdx.x * 128;
  const int grow = lane >> 2;
  const int gcol = (lane & 3) * 8;

  float4v acc[4][2];
#pragma unroll
  for (int i = 0; i < 4; ++i)
#pragma unroll
    for (int j = 0; j < 2; ++j) acc[i][j] = {0.f, 0.f, 0.f, 0.f};

  const u16* Abase = A + (size_t)m0 * K;
  const u16* Bbase = Bt + (size_t)n0 * K;

  for (int kt = 0; kt < K; kt += 32) {
    __syncthreads();
    gload16(Abase + (size_t)(w * 16 + grow) * K + kt + gcol, &Al[(w * 16) * 32]);
#pragma unroll
    for (int c = 0; c < 2; ++c)
      gload16(Bbase + (size_t)(w * 32 + c * 16 + grow) * K + kt + gcol,
              &Bl[(w * 32 + c * 16) * 32]);
    __syncthreads();
    bf16x8 af[4], bg[2];
#pragma unroll
    for (int i = 0; i < 4; ++i)
      af[i] = *reinterpret_cast<const bf16x8*>(&Al[(i * 16 + lr) * 32 + lg * 8]);
#pragma unroll
    for (int j = 0; j < 2; ++j)
      bg[j] = *reinterpret_cast<const bf16x8*>(&Bl[(w * 32 + j * 16 + lr) * 32 + lg * 8]);
#pragma unroll
    for (int i = 0; i < 4; ++i)
#pragma unroll
      for (int j = 0; j < 2; ++j)
        acc[i][j] = __builtin_amdgcn_mfma_f32_16x16x32_bf16(af[i], bg[j], acc[i][j], 0, 0, 0);
  }

#pragma unroll
  for (int i = 0; i < 4; ++i) {
    int rbase = m0 + i * 16 + lg * 4;
#pragma unroll
    for (int j = 0; j < 2; ++j) {
      int c = n0 + w * 32 + j * 16 + lr;
      float bv = bias[c];
#pragma unroll
      for (int jj = 0; jj < 4; ++jj) {
        int rr = rbase + jj;
        float v = acc[i][j][jj] + bv;
        if (ACT == 1) v = 0.5f * v * (1.0f + erff(v * 0.70710678118654752f));
        if (RES) v += resid[(size_t)rr * N + c];
        if (OUTF)
          reinterpret_cast<float*>(outp)[(size_t)rr * N + c] = v;
        else
          reinterpret_cast<u16*>(outp)[(size_t)rr * N + c] = f2b(v);
      }
    }
  }
}

// ------- fused flash attention, swapped-QK^T, pipelined -------------------
// qkv: (B,T,3,H,64) bf16, row stride 1536. out: (B,T,512) bf16.
// r7 winner (65.3 us): cvt_pk pack + permlane32_swap exchange, 4x
// ds_write_b64 V-scatter, setprio around MFMA. Occupancy capped at
// 2 waves/SIMD by register quantum (r1-r4 ledger).
// r8: XCD-aware block remap. Old grid mapping had linear id % 8 = q-tile,
// so the 8 blocks sharing one (b,h)'s K/V stream landed on 8 different
// XCDs -> each XCD L2 filled its own copy (FETCH 70 MB vs 33 ideal).
// New: bh = blockIdx.x + (y & 56), q-tile = y & 7 -> id % 8 = head;
// all 8 q-tiles of a (b,h) on one XCD, 2 MB K/V per XCD L2. Bijective.
template<int BIASF>
__global__ __launch_bounds__(256) void attn_kernel(
    const u16* __restrict__ qkv, const float* __restrict__ bias2,
    u16* __restrict__ out) {
  __shared__ u16 Vt[2][64 * 64];  // [buf][dv][key], slot-swizzled
  const int tid = threadIdx.x;
  const int lane = tid & 63;
  const int w = tid >> 6;
  const int hl = lane >> 5;
  const int l31 = lane & 31;
  const int bh = (int)blockIdx.x + ((int)blockIdx.y & 56);
  const int b = bh >> 3, hh = bh & 7;
  const int q0 = ((int)blockIdx.y & 7) * 128;
  const int qr = q0 + w * 32 + l31;
  const u16* base = qkv + (size_t)b * 1024 * 1536 + hh * 64;
  const float SC = 0.18033688011112042f;  // 0.125 * log2(e)

  bf16x8 qb[4];
  {
    const u16* qp = base + (size_t)qr * 1536 + hl * 8;
#pragma unroll
    for (int dc = 0; dc < 4; ++dc)
      qb[dc] = *reinterpret_cast<const bf16x8*>(qp + dc * 16);
  }

  const int vk4 = (tid >> 4) * 4;   // key group of 4 this thread stages
  const int dv0 = (tid & 15) * 4;   // dv chunk of 4

  f32x16 oA = {}, oB = {};
  float mreg = -1e30f, lsum = 0.f;

  // ---- prologue: V tile 0 -> Vt[0]; K tile 0 -> regs ----
  u16x4 vrow[4];
  {
    const u16* vp = base + (size_t)vk4 * 1536 + 1024 + dv0;
#pragma unroll
    for (int j = 0; j < 4; ++j)
      vrow[j] = *reinterpret_cast<const u16x4*>(vp + j * 1536);
  }
  bf16x8 ka[4], kb[4];
  {
    const u16* kp = base + (size_t)l31 * 1536 + 512 + hl * 8;
#pragma unroll
    for (int dc = 0; dc < 4; ++dc) {
      ka[dc] = *reinterpret_cast<const bf16x8*>(kp + dc * 16);
      kb[dc] = *reinterpret_cast<const bf16x8*>(kp + 32 * 1536 + dc * 16);
    }
  }
  {
    char* vb = (char*)Vt[0];
#pragma unroll
    for (int e = 0; e < 4; ++e) {
      int dv = dv0 + e;
      u16x4 wv = {vrow[0][e], vrow[1][e], vrow[2][e], vrow[3][e]};
      *reinterpret_cast<u16x4*>(vb + dv * 128 +
          ((vk4 * 2) ^ (((dv + (dv >> 3)) & 7) << 4))) = wv;
    }
  }
  __syncthreads();

  for (int t = 0; t < 16; ++t) {
    const int kt = t * 64;
    const int cur = t & 1;

    // S^T = K·Q^T from registers
    f32x16 sA = {}, sB = {};
    __builtin_amdgcn_s_setprio(1);
#pragma unroll
    for (int dc = 0; dc < 4; ++dc) {
      sA = __builtin_amdgcn_mfma_f32_32x32x16_bf16(ka[dc], qb[dc], sA, 0, 0, 0);
      sB = __builtin_amdgcn_mfma_f32_32x32x16_bf16(kb[dc], qb[dc], sB, 0, 0, 0);
    }
    __builtin_amdgcn_s_setprio(0);
    // prefetch next K and V tiles (latency hides under softmax+PV)
    if (t < 15) {
      const u16* kp = base + (size_t)(kt + 64 + l31) * 1536 + 512 + hl * 8;
#pragma unroll
      for (int dc = 0; dc < 4; ++dc) {
        ka[dc] = *reinterpret_cast<const bf16x8*>(kp + dc * 16);
        kb[dc] = *reinterpret_cast<const bf16x8*>(kp + 32 * 1536 + dc * 16);
      }
      const u16* vp = base + (size_t)(kt + 64 + vk4) * 1536 + 1024 + dv0;
#pragma unroll
      for (int j = 0; j < 4; ++j)
        vrow[j] = *reinterpret_cast<const u16x4*>(vp + j * 1536);
    }

    // scale (+bias), exp2 domain
#pragma unroll
    for (int r = 0; r < 16; ++r) {
      int key = (r & 3) + 8 * (r >> 2) + 4 * hl;
      if (BIASF) {
        sA[r] = fmaf(sA[r], SC, bias2[qr - kt - key + 1023]);
        sB[r] = fmaf(sB[r], SC, bias2[qr - kt - 32 - key + 1023]);
      } else {
        sA[r] *= SC;
        sB[r] *= SC;
      }
    }

    // online softmax with defer-max (THR = 8*log2e)
    float mx = fmaxf(sA[0], sB[0]);
#pragma unroll
    for (int r = 1; r < 16; ++r) mx = fmaxf(mx, fmaxf(sA[r], sB[r]));
    mx = fmaxf(mx, __shfl_xor(mx, 32));
    if (!__all(mx - mreg <= 11.5416f)) {
      float mn = fmaxf(mreg, mx);
      float al = exp2f(mreg - mn);
      mreg = mn;
      lsum *= al;
      oA *= al;
      oB *= al;
    }
    float ps = 0.f;
#pragma unroll
    for (int r = 0; r < 16; ++r) {
      float pa = exp2f(sA[r] - mreg);
      float pb = exp2f(sB[r] - mreg);
      sA[r] = pa; sB[r] = pb;
      ps += pa + pb;
    }
    lsum += ps;

    // pack P to bf16 (v_cvt_pk_bf16_f32, RNE) and exchange halves via
    // v_permlane32_swap_b32 (r7: 80 -> 24 ops per tile).
    u32 wa[8], wb[8];
#pragma unroll
    for (int i = 0; i < 8; ++i) {
      asm("v_cvt_pk_bf16_f32 %0, %1, %2"
          : "=v"(wa[i]) : "v"(sA[2 * i]), "v"(sA[2 * i + 1]));
      asm("v_cvt_pk_bf16_f32 %0, %1, %2"
          : "=v"(wb[i]) : "v"(sB[2 * i]), "v"(sB[2 * i + 1]));
    }
#pragma unroll
    for (int i = 0; i < 2; ++i) {
      asm("v_permlane32_swap_b32 %0, %1" : "+v"(wa[i]), "+v"(wa[i + 2]));
      asm("v_permlane32_swap_b32 %0, %1" : "+v"(wa[i + 4]), "+v"(wa[i + 6]));
      asm("v_permlane32_swap_b32 %0, %1" : "+v"(wb[i]), "+v"(wb[i + 2]));
      asm("v_permlane32_swap_b32 %0, %1" : "+v"(wb[i + 4]), "+v"(wb[i + 6]));
    }
    u32x4 f00 = {wa[0], wa[1], wa[2], wa[3]};
    u32x4 f01 = {wa[4], wa[5], wa[6], wa[7]};
    u32x4 f10 = {wb[0], wb[1], wb[2], wb[3]};
    u32x4 f11 = {wb[4], wb[5], wb[6], wb[7]};
    bf16x8 p00 = __builtin_bit_cast(bf16x8, f00);
    bf16x8 p01 = __builtin_bit_cast(bf16x8, f01);
    bf16x8 p10 = __builtin_bit_cast(bf16x8, f10);
    bf16x8 p11 = __builtin_bit_cast(bf16x8, f11);

    // O^T += V^T · P from Vt[cur]
    const char* vbc = (const char*)Vt[cur];
    const int sl0 = ((l31 + (l31 >> 3)) & 7) << 4;
    const int sl1 = (((32 + l31) + ((32 + l31) >> 3)) & 7) << 4;
    const char* vp0 = vbc + l31 * 128;
    const char* vp1 = vbc + (32 + l31) * 128;
    const int cb = hl * 16;
    bf16x8 va;
    __builtin_amdgcn_s_setprio(1);
    va = *reinterpret_cast<const bf16x8*>(vp0 + ((cb + 0) ^ sl0));
    oA = __builtin_amdgcn_mfma_f32_32x32x16_bf16(va, p00, oA, 0, 0, 0);
    va = *reinterpret_cast<const bf16x8*>(vp0 + ((cb + 32) ^ sl0));
    oA = __builtin_amdgcn_mfma_f32_32x32x16_bf16(va, p01, oA, 0, 0, 0);
    va = *reinterpret_cast<const bf16x8*>(vp0 + ((cb + 64) ^ sl0));
    oA = __builtin_amdgcn_mfma_f32_32x32x16_bf16(va, p10, oA, 0, 0, 0);
    va = *reinterpret_cast<const bf16x8*>(vp0 + ((cb + 96) ^ sl0));
    oA = __builtin_amdgcn_mfma_f32_32x32x16_bf16(va, p11, oA, 0, 0, 0);
    va = *reinterpret_cast<const bf16x8*>(vp1 + ((cb + 0) ^ sl1));
    oB = __builtin_amdgcn_mfma_f32_32x32x16_bf16(va, p00, oB, 0, 0, 0);
    va = *reinterpret_cast<const bf16x8*>(vp1 + ((cb + 32) ^ sl1));
    oB = __builtin_amdgcn_mfma_f32_32x32x16_bf16(va, p01, oB, 0, 0, 0);
    va = *reinterpret_cast<const bf16x8*>(vp1 + ((cb + 64) ^ sl1));
    oB = __builtin_amdgcn_mfma_f32_32x32x16_bf16(va, p10, oB, 0, 0, 0);
    va = *reinterpret_cast<const bf16x8*>(vp1 + ((cb + 96) ^ sl1));
    oB = __builtin_amdgcn_mfma_f32_32x32x16_bf16(va, p11, oB, 0, 0, 0);
    __builtin_amdgcn_s_setprio(0);

    // scatter next V tile into the other buffer (4x ds_write_b64)
    if (t < 15) {
      char* vb = (char*)Vt[cur ^ 1];
#pragma unroll
      for (int e = 0; e < 4; ++e) {
        int dv = dv0 + e;
        u16x4 wv = {vrow[0][e], vrow[1][e], vrow[2][e], vrow[3][e]};
        *reinterpret_cast<u16x4*>(vb + dv * 128 +
            ((vk4 * 2) ^ (((dv + (dv >> 3)) & 7) << 4))) = wv;
      }
    }
    __syncthreads();
  }

  lsum += __shfl_xor(lsum, 32);
  float inv = 1.f / lsum;
  size_t orow = (size_t)(b * 1024 + qr) * 512 + hh * 64;
#pragma unroll
  for (int g = 0; g < 4; ++g) {
    u16x4 pk;
#pragma unroll
    for (int e = 0; e < 4; ++e) pk[e] = f2b(oA[g * 4 + e] * inv);
    *reinterpret_cast<u16x4*>(out + orow + g * 8 + hl * 4) = pk;
#pragma unroll
    for (int e = 0; e < 4; ++e) pk[e] = f2b(oB[g * 4 + e] * inv);
    *reinterpret_cast<u16x4*>(out + orow + 32 + g * 8 + hl * 4) = pk;
  }
}

extern "C" void kernel_launch(void* const* d_in, const int* in_sizes, int n_in,
                              void* d_out, int out_size, void* d_ws, size_t ws_size,
                              hipStream_t stream) {
  (void)in_sizes; (void)n_in; (void)out_size; (void)ws_size;
  const float* x        = (const float*)d_in[0];
  const float* ns_g     = (const float*)d_in[2];
  const float* ns_b     = (const float*)d_in[3];
  const float* nt_g     = (const float*)d_in[4];
  const float* nt_b     = (const float*)d_in[5];
  const float* nf_g     = (const float*)d_in[6];
  const float* nf_b     = (const float*)d_in[7];
  const float* s_qkv_w  = (const float*)d_in[8];
  const float* s_qkv_b  = (const float*)d_in[9];
  const float* s_proj_w = (const float*)d_in[10];
  const float* s_proj_b = (const float*)d_in[11];
  const float* t_qkv_w  = (const float*)d_in[12];
  const float* t_qkv_b  = (const float*)d_in[13];
  const float* t_proj_w = (const float*)d_in[14];
  const float* t_proj_b = (const float*)d_in[15];
  const float* rpe_tab  = (const float*)d_in[16];
  const float* rpe_w    = (const float*)d_in[17];
  const float* ff_w1    = (const float*)d_in[18];
  const float* ff_b1    = (const float*)d_in[19];
  const float* ff_w2    = (const float*)d_in[20];
  const float* ff_b2    = (const float*)d_in[21];

  char* ws = (char*)d_ws;
  float* xr    = (float*)(ws);                 // 16.78 MB fp32 residual
  u16*   lnb   = (u16*)(ws + 16777216);        // 8.39 MB bf16 LN output
  u16*   big   = (u16*)(ws + 25165824);        // qkv bf16 / ffn hidden
  float* bias2 = (float*)(ws + 50331648);      // 8 KB (past qkv end; dead before ffn)
  u16*   wT    = (u16*)(ws + 58720256);        // 8.39 MB transposed bf16 weights
  u16* sqkvT  = wT;
  u16* tqkvT  = wT + 786432;
  u16* sprojT = wT + 1572864;
  u16* tprojT = wT + 1835008;
  u16* ff1T   = wT + 2097152;
  u16* ff2T   = wT + 3145728;
  u16* ao     = (u16*)d_out;     // attention output scratch
  float* outp = (float*)d_out;

  // fused prep: 6 transposes + bias + spatial LN in ONE dispatch
  prep_kernel<<<6152, 256, 0, stream>>>(
      x, ns_g, ns_b, lnb,
      s_qkv_w, sqkvT, t_qkv_w, tqkvT, s_proj_w, sprojT, t_proj_w, tprojT,
      ff_w1, ff1T, ff_w2, ff2T, rpe_tab, rpe_w, bias2);

  // --- spatial attention block ---
  gemm_kernel<0, 0, 0><<<dim3(12, 64), 256, 0, stream>>>(
      lnb, sqkvT, s_qkv_b, nullptr, big, 8192, 1536, 512);
  attn_kernel<0><<<dim3(8, 64), 256, 0, stream>>>(big, nullptr, ao);
  gemm64_kernel<0, 1, 1><<<dim3(4, 128), 256, 0, stream>>>(
      ao, sprojT, s_proj_b, x, xr, 8192, 512, 512);
  // --- temporal attention block ---
  ln_kernel<<<2048, 256, 0, stream>>>(xr, nt_g, nt_b, lnb);
  gemm_kernel<0, 0, 0><<<dim3(12, 64), 256, 0, stream>>>(
      lnb, tqkvT, t_qkv_b, nullptr, big, 8192, 1536, 512);
  attn_kernel<1><<<dim3(8, 64), 256, 0, stream>>>(big, bias2, ao);
  gemm64_kernel<0, 1, 1><<<dim3(4, 128), 256, 0, stream>>>(
      ao, tprojT, t_proj_b, xr, xr, 8192, 512, 512);
  // --- FFN block ---
  ln_kernel<<<2048, 256, 0, stream>>>(xr, nf_g, nf_b, lnb);
  gemm_kernel<1, 0, 0><<<dim3(16, 64), 256, 0, stream>>>(
      lnb, ff1T, ff_b1, nullptr, big, 8192, 2048, 512);
  gemm64_kernel<0, 1, 1><<<dim3(4, 128), 256, 0, stream>>>(
      big, ff2T, ff_b2, xr, outp, 8192, 512, 2048);
}

// Round 9
// 293.843 us; speedup vs baseline: 1.1528x; 1.0402x over previous
//
#include <hip/hip_runtime.h>
#include <hip/hip_bf16.h>

typedef unsigned short u16;
typedef unsigned int u32;
typedef __bf16 bf16x8 __attribute__((ext_vector_type(8)));
typedef float float4v __attribute__((ext_vector_type(4)));
typedef float f32x16 __attribute__((ext_vector_type(16)));
typedef u32 u32x4 __attribute__((ext_vector_type(4)));
typedef u16 u16x4 __attribute__((ext_vector_type(4)));
typedef u16 u16x8 __attribute__((ext_vector_type(8)));

__device__ __forceinline__ u16 f2b(float f) {
  u32 u = __float_as_uint(f);
  u += 0x7fffu + ((u >> 16) & 1u);
  return (u16)(u >> 16);
}

__device__ __forceinline__ void gload16(const void* g, void* l) {
  __builtin_amdgcn_global_load_lds(
      (const __attribute__((address_space(1))) void*)g,
      (__attribute__((address_space(3))) void*)l, 16, 0, 0);
}

// ------- fused prep: 6 weight transposes + rel-pos bias + spatial LN ------
// (r8 win: one dispatch replaces 8 small serialized launches, ~+19 us)
__global__ __launch_bounds__(256) void prep_kernel(
    const float* __restrict__ x, const float* __restrict__ ns_g,
    const float* __restrict__ ns_b, u16* __restrict__ lnb,
    const float* __restrict__ sqkvW, u16* __restrict__ sqkvT,
    const float* __restrict__ tqkvW, u16* __restrict__ tqkvT,
    const float* __restrict__ sprojW, u16* __restrict__ sprojT,
    const float* __restrict__ tprojW, u16* __restrict__ tprojT,
    const float* __restrict__ ff1W, u16* __restrict__ ff1T,
    const float* __restrict__ ff2W, u16* __restrict__ ff2T,
    const float* __restrict__ rpe_tab, const float* __restrict__ rpe_w,
    float* __restrict__ bias2) {
  __shared__ float t[32][33];
  const int bid = blockIdx.x;
  const int tid = threadIdx.x;

  if (bid < 2048) {  // ---- spatial LayerNorm ----
    int row = bid * 4 + (tid >> 6);
    int lane = tid & 63;
    const float* xp = x + (size_t)row * 512 + lane * 8;
    float4v v0 = *reinterpret_cast<const float4v*>(xp);
    float4v v1 = *reinterpret_cast<const float4v*>(xp + 4);
    float s = v0[0] + v0[1] + v0[2] + v0[3] + v1[0] + v1[1] + v1[2] + v1[3];
    float q = v0[0]*v0[0] + v0[1]*v0[1] + v0[2]*v0[2] + v0[3]*v0[3]
            + v1[0]*v1[0] + v1[1]*v1[1] + v1[2]*v1[2] + v1[3]*v1[3];
#pragma unroll
    for (int d = 1; d < 64; d <<= 1) { s += __shfl_xor(s, d); q += __shfl_xor(q, d); }
    float mu = s * (1.f / 512.f);
    float var = q * (1.f / 512.f) - mu * mu;
    float rstd = rsqrtf(var + 1e-5f);
    const float* gp = ns_g + lane * 8;
    const float* bp = ns_b + lane * 8;
    u16x8 o;
#pragma unroll
    for (int e = 0; e < 4; ++e) o[e] = f2b((v0[e] - mu) * rstd * gp[e] + bp[e]);
#pragma unroll
    for (int e = 0; e < 4; ++e) o[4 + e] = f2b((v1[e] - mu) * rstd * gp[4 + e] + bp[4 + e]);
    *reinterpret_cast<u16x8*>(lnb + (size_t)row * 512 + lane * 8) = o;
    return;
  }
  if (bid >= 6144) {  // ---- rel-pos bias ----
    int i = (bid - 6144) * 256 + tid;
    if (i >= 2047) return;
    const float* row = rpe_tab + (size_t)(i + 976) * 64;
    float s = 0.f;
#pragma unroll
    for (int d = 0; d < 64; ++d) s += row[d] * rpe_w[d];
    bias2[i] = s * 1.4426950408889634f;
    return;
  }
  // ---- weight transpose+convert ----
  const float* tin; u16* tout; int R, C, w, tilesx;
  if (bid < 2816)      { tin = sqkvW;  tout = sqkvT;  R = 512;  C = 1536; w = bid - 2048; tilesx = 48; }
  else if (bid < 3584) { tin = tqkvW;  tout = tqkvT;  R = 512;  C = 1536; w = bid - 2816; tilesx = 48; }
  else if (bid < 3840) { tin = sprojW; tout = sprojT; R = 512;  C = 512;  w = bid - 3584; tilesx = 16; }
  else if (bid < 4096) { tin = tprojW; tout = tprojT; R = 512;  C = 512;  w = bid - 3840; tilesx = 16; }
  else if (bid < 5120) { tin = ff1W;   tout = ff1T;   R = 512;  C = 2048; w = bid - 4096; tilesx = 64; }
  else                 { tin = ff2W;   tout = ff2T;   R = 2048; C = 512;  w = bid - 5120; tilesx = 16; }
  int c0 = (w % tilesx) * 32, r0 = (w / tilesx) * 32;
  int tx = tid & 31, ty = tid >> 5;
  for (int i = ty; i < 32; i += 8)
    t[i][tx] = tin[(size_t)(r0 + i) * C + c0 + tx];
  __syncthreads();
  for (int i = ty; i < 32; i += 8)
    tout[(size_t)(c0 + i) * R + r0 + tx] = f2b(t[tx][i]);
}

// ------- LayerNorm: fp32 in -> bf16 out, one wave per row of 512 ----------
__global__ __launch_bounds__(256) void ln_kernel(
    const float* __restrict__ xr, const float* __restrict__ g,
    const float* __restrict__ bta, u16* __restrict__ out) {
  int row = blockIdx.x * 4 + (threadIdx.x >> 6);
  int lane = threadIdx.x & 63;
  const float* xp = xr + (size_t)row * 512 + lane * 8;
  float4v v0 = *reinterpret_cast<const float4v*>(xp);
  float4v v1 = *reinterpret_cast<const float4v*>(xp + 4);
  float s = v0[0] + v0[1] + v0[2] + v0[3] + v1[0] + v1[1] + v1[2] + v1[3];
  float q = v0[0]*v0[0] + v0[1]*v0[1] + v0[2]*v0[2] + v0[3]*v0[3]
          + v1[0]*v1[0] + v1[1]*v1[1] + v1[2]*v1[2] + v1[3]*v1[3];
#pragma unroll
  for (int d = 1; d < 64; d <<= 1) { s += __shfl_xor(s, d); q += __shfl_xor(q, d); }
  float mu = s * (1.f / 512.f);
  float var = q * (1.f / 512.f) - mu * mu;
  float rstd = rsqrtf(var + 1e-5f);
  const float* gp = g + lane * 8;
  const float* bp = bta + lane * 8;
  u16x8 o;
#pragma unroll
  for (int e = 0; e < 4; ++e) o[e] = f2b((v0[e] - mu) * rstd * gp[e] + bp[e]);
#pragma unroll
  for (int e = 0; e < 4; ++e) o[4 + e] = f2b((v1[e] - mu) * rstd * gp[4 + e] + bp[4 + e]);
  *reinterpret_cast<u16x8*>(out + (size_t)row * 512 + lane * 8) = o;
}

// ------- MFMA GEMM BM=128,BN=128, BK=64 (2 sub-tiles per barrier pair) ----
// r9: halve barrier-drain count vs m97 structure. Each 64-wide K-step
// stages two 32-wide sub-tiles (layout per sub-tile identical to the
// BK=32 version: same stride, same bank behavior, same gload addressing),
// then runs two MFMA passes. Barriers per K=512: 32 -> 16.
template<int ACT, int RES, int OUTF>
__global__ __launch_bounds__(256) void gemm_kernel(
    const u16* __restrict__ A, const u16* __restrict__ Bt,
    const float* __restrict__ bias, const float* resid,
    void* outp, int M, int N, int K) {
  __shared__ u16 Al[2][128 * 32];
  __shared__ u16 Bl[2][128 * 32];
  const int tid = threadIdx.x;
  const int lane = tid & 63;
  const int w = tid >> 6;
  const int wr = w >> 1, wc = w & 1;
  const int lg = lane >> 4, lr = lane & 15;
  const int m0 = blockIdx.y * 128, n0 = blockIdx.x * 128;
  const int gcol = (lane & 3) * 8;

  float4v acc[4][4];
#pragma unroll
  for (int i = 0; i < 4; ++i)
#pragma unroll
    for (int j = 0; j < 4; ++j) acc[i][j] = {0.f, 0.f, 0.f, 0.f};

  const u16* Abase = A + (size_t)m0 * K;
  const u16* Bbase = Bt + (size_t)n0 * K;
  const int grow = lane >> 2;

  for (int kt = 0; kt < K; kt += 64) {
    __syncthreads();
#pragma unroll
    for (int kk = 0; kk < 2; ++kk)
#pragma unroll
      for (int c = 0; c < 2; ++c) {
        int r = w * 32 + c * 16 + grow;
        gload16(Abase + (size_t)r * K + kt + kk * 32 + gcol,
                &Al[kk][(w * 32 + c * 16) * 32]);
        gload16(Bbase + (size_t)r * K + kt + kk * 32 + gcol,
                &Bl[kk][(w * 32 + c * 16) * 32]);
      }
    __syncthreads();
#pragma unroll
    for (int kk = 0; kk < 2; ++kk) {
      bf16x8 af[4], bg[4];
#pragma unroll
      for (int i = 0; i < 4; ++i)
        af[i] = *reinterpret_cast<const bf16x8*>(&Al[kk][(wr * 64 + i * 16 + lr) * 32 + lg * 8]);
#pragma unroll
      for (int j = 0; j < 4; ++j)
        bg[j] = *reinterpret_cast<const bf16x8*>(&Bl[kk][(wc * 64 + j * 16 + lr) * 32 + lg * 8]);
#pragma unroll
      for (int i = 0; i < 4; ++i)
#pragma unroll
        for (int j = 0; j < 4; ++j)
          acc[i][j] = __builtin_amdgcn_mfma_f32_16x16x32_bf16(af[i], bg[j], acc[i][j], 0, 0, 0);
    }
  }

#pragma unroll
  for (int i = 0; i < 4; ++i) {
    int rbase = m0 + wr * 64 + i * 16 + lg * 4;
#pragma unroll
    for (int j = 0; j < 4; ++j) {
      int c = n0 + wc * 64 + j * 16 + lr;
      float bv = bias[c];
#pragma unroll
      for (int jj = 0; jj < 4; ++jj) {
        int rr = rbase + jj;
        float v = acc[i][j][jj] + bv;
        if (ACT == 1) v = 0.5f * v * (1.0f + erff(v * 0.70710678118654752f));
        if (RES) v += resid[(size_t)rr * N + c];
        if (OUTF)
          reinterpret_cast<float*>(outp)[(size_t)rr * N + c] = v;
        else
          reinterpret_cast<u16*>(outp)[(size_t)rr * N + c] = f2b(v);
      }
    }
  }
}

// ------- MFMA GEMM BM=64,BN=128, BK=64 (2 sub-tiles per barrier pair) -----
template<int ACT, int RES, int OUTF>
__global__ __launch_bounds__(256) void gemm64_kernel(
    const u16* __restrict__ A, const u16* __restrict__ Bt,
    const float* __restrict__ bias, const float* resid,
    void* outp, int M, int N, int K) {
  __shared__ u16 Al[2][64 * 32];
  __shared__ u16 Bl[2][128 * 32];
  const int tid = threadIdx.x;
  const int lane = tid & 63;
  const int w = tid >> 6;
  const int lg = lane >> 4, lr = lane & 15;
  const int m0 = blockIdx.y * 64, n0 = blockIdx.x * 128;
  const int grow = lane >> 2;
  const int gcol = (lane & 3) * 8;

  float4v acc[4][2];
#pragma unroll
  for (int i = 0; i < 4; ++i)
#pragma unroll
    for (int j = 0; j < 2; ++j) acc[i][j] = {0.f, 0.f, 0.f, 0.f};

  const u16* Abase = A + (size_t)m0 * K;
  const u16* Bbase = Bt + (size_t)n0 * K;

  for (int kt = 0; kt < K; kt += 64) {
    __syncthreads();
#pragma unroll
    for (int kk = 0; kk < 2; ++kk) {
      gload16(Abase + (size_t)(w * 16 + grow) * K + kt + kk * 32 + gcol,
              &Al[kk][(w * 16) * 32]);
#pragma unroll
      for (int c = 0; c < 2; ++c)
        gload16(Bbase + (size_t)(w * 32 + c * 16 + grow) * K + kt + kk * 32 + gcol,
                &Bl[kk][(w * 32 + c * 16) * 32]);
    }
    __syncthreads();
#pragma unroll
    for (int kk = 0; kk < 2; ++kk) {
      bf16x8 af[4], bg[2];
#pragma unroll
      for (int i = 0; i < 4; ++i)
        af[i] = *reinterpret_cast<const bf16x8*>(&Al[kk][(i * 16 + lr) * 32 + lg * 8]);
#pragma unroll
      for (int j = 0; j < 2; ++j)
        bg[j] = *reinterpret_cast<const bf16x8*>(&Bl[kk][(w * 32 + j * 16 + lr) * 32 + lg * 8]);
#pragma unroll
      for (int i = 0; i < 4; ++i)
#pragma unroll
        for (int j = 0; j < 2; ++j)
          acc[i][j] = __builtin_amdgcn_mfma_f32_16x16x32_bf16(af[i], bg[j], acc[i][j], 0, 0, 0);
    }
  }

#pragma unroll
  for (int i = 0; i < 4; ++i) {
    int rbase = m0 + i * 16 + lg * 4;
#pragma unroll
    for (int j = 0; j < 2; ++j) {
      int c = n0 + w * 32 + j * 16 + lr;
      float bv = bias[c];
#pragma unroll
      for (int jj = 0; jj < 4; ++jj) {
        int rr = rbase + jj;
        float v = acc[i][j][jj] + bv;
        if (ACT == 1) v = 0.5f * v * (1.0f + erff(v * 0.70710678118654752f));
        if (RES) v += resid[(size_t)rr * N + c];
        if (OUTF)
          reinterpret_cast<float*>(outp)[(size_t)rr * N + c] = v;
        else
          reinterpret_cast<u16*>(outp)[(size_t)rr * N + c] = f2b(v);
      }
    }
  }
}

// ------- fused flash attention, swapped-QK^T, pipelined -------------------
// qkv: (B,T,3,H,64) bf16, row stride 1536. out: (B,T,512) bf16.
// r7 winner (65.3 us): cvt_pk pack + permlane32_swap exchange, 4x
// ds_write_b64 V-scatter, setprio around MFMA. Occupancy capped at
// 2 waves/SIMD by register quantum (r1-r4 ledger). r8's XCD remap cut
// FETCH 5.6x but cost ~3% time (not HBM-bound) -> reverted in r9.
template<int BIASF>
__global__ __launch_bounds__(256) void attn_kernel(
    const u16* __restrict__ qkv, const float* __restrict__ bias2,
    u16* __restrict__ out) {
  __shared__ u16 Vt[2][64 * 64];  // [buf][dv][key], slot-swizzled
  const int tid = threadIdx.x;
  const int lane = tid & 63;
  const int w = tid >> 6;
  const int hl = lane >> 5;
  const int l31 = lane & 31;
  const int bh = blockIdx.y;
  const int b = bh >> 3, hh = bh & 7;
  const int q0 = blockIdx.x * 128;
  const int qr = q0 + w * 32 + l31;
  const u16* base = qkv + (size_t)b * 1024 * 1536 + hh * 64;
  const float SC = 0.18033688011112042f;  // 0.125 * log2(e)

  bf16x8 qb[4];
  {
    const u16* qp = base + (size_t)qr * 1536 + hl * 8;
#pragma unroll
    for (int dc = 0; dc < 4; ++dc)
      qb[dc] = *reinterpret_cast<const bf16x8*>(qp + dc * 16);
  }

  const int vk4 = (tid >> 4) * 4;   // key group of 4 this thread stages
  const int dv0 = (tid & 15) * 4;   // dv chunk of 4

  f32x16 oA = {}, oB = {};
  float mreg = -1e30f, lsum = 0.f;

  // ---- prologue: V tile 0 -> Vt[0]; K tile 0 -> regs ----
  u16x4 vrow[4];
  {
    const u16* vp = base + (size_t)vk4 * 1536 + 1024 + dv0;
#pragma unroll
    for (int j = 0; j < 4; ++j)
      vrow[j] = *reinterpret_cast<const u16x4*>(vp + j * 1536);
  }
  bf16x8 ka[4], kb[4];
  {
    const u16* kp = base + (size_t)l31 * 1536 + 512 + hl * 8;
#pragma unroll
    for (int dc = 0; dc < 4; ++dc) {
      ka[dc] = *reinterpret_cast<const bf16x8*>(kp + dc * 16);
      kb[dc] = *reinterpret_cast<const bf16x8*>(kp + 32 * 1536 + dc * 16);
    }
  }
  {
    char* vb = (char*)Vt[0];
#pragma unroll
    for (int e = 0; e < 4; ++e) {
      int dv = dv0 + e;
      u16x4 wv = {vrow[0][e], vrow[1][e], vrow[2][e], vrow[3][e]};
      *reinterpret_cast<u16x4*>(vb + dv * 128 +
          ((vk4 * 2) ^ (((dv + (dv >> 3)) & 7) << 4))) = wv;
    }
  }
  __syncthreads();

  for (int t = 0; t < 16; ++t) {
    const int kt = t * 64;
    const int cur = t & 1;

    // S^T = K·Q^T from registers
    f32x16 sA = {}, sB = {};
    __builtin_amdgcn_s_setprio(1);
#pragma unroll
    for (int dc = 0; dc < 4; ++dc) {
      sA = __builtin_amdgcn_mfma_f32_32x32x16_bf16(ka[dc], qb[dc], sA, 0, 0, 0);
      sB = __builtin_amdgcn_mfma_f32_32x32x16_bf16(kb[dc], qb[dc], sB, 0, 0, 0);
    }
    __builtin_amdgcn_s_setprio(0);
    // prefetch next K and V tiles (latency hides under softmax+PV)
    if (t < 15) {
      const u16* kp = base + (size_t)(kt + 64 + l31) * 1536 + 512 + hl * 8;
#pragma unroll
      for (int dc = 0; dc < 4; ++dc) {
        ka[dc] = *reinterpret_cast<const bf16x8*>(kp + dc * 16);
        kb[dc] = *reinterpret_cast<const bf16x8*>(kp + 32 * 1536 + dc * 16);
      }
      const u16* vp = base + (size_t)(kt + 64 + vk4) * 1536 + 1024 + dv0;
#pragma unroll
      for (int j = 0; j < 4; ++j)
        vrow[j] = *reinterpret_cast<const u16x4*>(vp + j * 1536);
    }

    // scale (+bias), exp2 domain
#pragma unroll
    for (int r = 0; r < 16; ++r) {
      int key = (r & 3) + 8 * (r >> 2) + 4 * hl;
      if (BIASF) {
        sA[r] = fmaf(sA[r], SC, bias2[qr - kt - key + 1023]);
        sB[r] = fmaf(sB[r], SC, bias2[qr - kt - 32 - key + 1023]);
      } else {
        sA[r] *= SC;
        sB[r] *= SC;
      }
    }

    // online softmax with defer-max (THR = 8*log2e)
    float mx = fmaxf(sA[0], sB[0]);
#pragma unroll
    for (int r = 1; r < 16; ++r) mx = fmaxf(mx, fmaxf(sA[r], sB[r]));
    mx = fmaxf(mx, __shfl_xor(mx, 32));
    if (!__all(mx - mreg <= 11.5416f)) {
      float mn = fmaxf(mreg, mx);
      float al = exp2f(mreg - mn);
      mreg = mn;
      lsum *= al;
      oA *= al;
      oB *= al;
    }
    float ps = 0.f;
#pragma unroll
    for (int r = 0; r < 16; ++r) {
      float pa = exp2f(sA[r] - mreg);
      float pb = exp2f(sB[r] - mreg);
      sA[r] = pa; sB[r] = pb;
      ps += pa + pb;
    }
    lsum += ps;

    // pack P to bf16 (v_cvt_pk_bf16_f32, RNE) and exchange halves via
    // v_permlane32_swap_b32 (r7: 80 -> 24 ops per tile).
    u32 wa[8], wb[8];
#pragma unroll
    for (int i = 0; i < 8; ++i) {
      asm("v_cvt_pk_bf16_f32 %0, %1, %2"
          : "=v"(wa[i]) : "v"(sA[2 * i]), "v"(sA[2 * i + 1]));
      asm("v_cvt_pk_bf16_f32 %0, %1, %2"
          : "=v"(wb[i]) : "v"(sB[2 * i]), "v"(sB[2 * i + 1]));
    }
#pragma unroll
    for (int i = 0; i < 2; ++i) {
      asm("v_permlane32_swap_b32 %0, %1" : "+v"(wa[i]), "+v"(wa[i + 2]));
      asm("v_permlane32_swap_b32 %0, %1" : "+v"(wa[i + 4]), "+v"(wa[i + 6]));
      asm("v_permlane32_swap_b32 %0, %1" : "+v"(wb[i]), "+v"(wb[i + 2]));
      asm("v_permlane32_swap_b32 %0, %1" : "+v"(wb[i + 4]), "+v"(wb[i + 6]));
    }
    u32x4 f00 = {wa[0], wa[1], wa[2], wa[3]};
    u32x4 f01 = {wa[4], wa[5], wa[6], wa[7]};
    u32x4 f10 = {wb[0], wb[1], wb[2], wb[3]};
    u32x4 f11 = {wb[4], wb[5], wb[6], wb[7]};
    bf16x8 p00 = __builtin_bit_cast(bf16x8, f00);
    bf16x8 p01 = __builtin_bit_cast(bf16x8, f01);
    bf16x8 p10 = __builtin_bit_cast(bf16x8, f10);
    bf16x8 p11 = __builtin_bit_cast(bf16x8, f11);

    // O^T += V^T · P from Vt[cur]
    const char* vbc = (const char*)Vt[cur];
    const int sl0 = ((l31 + (l31 >> 3)) & 7) << 4;
    const int sl1 = (((32 + l31) + ((32 + l31) >> 3)) & 7) << 4;
    const char* vp0 = vbc + l31 * 128;
    const char* vp1 = vbc + (32 + l31) * 128;
    const int cb = hl * 16;
    bf16x8 va;
    __builtin_amdgcn_s_setprio(1);
    va = *reinterpret_cast<const bf16x8*>(vp0 + ((cb + 0) ^ sl0));
    oA = __builtin_amdgcn_mfma_f32_32x32x16_bf16(va, p00, oA, 0, 0, 0);
    va = *reinterpret_cast<const bf16x8*>(vp0 + ((cb + 32) ^ sl0));
    oA = __builtin_amdgcn_mfma_f32_32x32x16_bf16(va, p01, oA, 0, 0, 0);
    va = *reinterpret_cast<const bf16x8*>(vp0 + ((cb + 64) ^ sl0));
    oA = __builtin_amdgcn_mfma_f32_32x32x16_bf16(va, p10, oA, 0, 0, 0);
    va = *reinterpret_cast<const bf16x8*>(vp0 + ((cb + 96) ^ sl0));
    oA = __builtin_amdgcn_mfma_f32_32x32x16_bf16(va, p11, oA, 0, 0, 0);
    va = *reinterpret_cast<const bf16x8*>(vp1 + ((cb + 0) ^ sl1));
    oB = __builtin_amdgcn_mfma_f32_32x32x16_bf16(va, p00, oB, 0, 0, 0);
    va = *reinterpret_cast<const bf16x8*>(vp1 + ((cb + 32) ^ sl1));
    oB = __builtin_amdgcn_mfma_f32_32x32x16_bf16(va, p01, oB, 0, 0, 0);
    va = *reinterpret_cast<const bf16x8*>(vp1 + ((cb + 64) ^ sl1));
    oB = __builtin_amdgcn_mfma_f32_32x32x16_bf16(va, p10, oB, 0, 0, 0);
    va = *reinterpret_cast<const bf16x8*>(vp1 + ((cb + 96) ^ sl1));
    oB = __builtin_amdgcn_mfma_f32_32x32x16_bf16(va, p11, oB, 0, 0, 0);
    __builtin_amdgcn_s_setprio(0);

    // scatter next V tile into the other buffer (4x ds_write_b64)
    if (t < 15) {
      char* vb = (char*)Vt[cur ^ 1];
#pragma unroll
      for (int e = 0; e < 4; ++e) {
        int dv = dv0 + e;
        u16x4 wv = {vrow[0][e], vrow[1][e], vrow[2][e], vrow[3][e]};
        *reinterpret_cast<u16x4*>(vb + dv * 128 +
            ((vk4 * 2) ^ (((dv + (dv >> 3)) & 7) << 4))) = wv;
      }
    }
    __syncthreads();
  }

  lsum += __shfl_xor(lsum, 32);
  float inv = 1.f / lsum;
  size_t orow = (size_t)(b * 1024 + qr) * 512 + hh * 64;
#pragma unroll
  for (int g = 0; g < 4; ++g) {
    u16x4 pk;
#pragma unroll
    for (int e = 0; e < 4; ++e) pk[e] = f2b(oA[g * 4 + e] * inv);
    *reinterpret_cast<u16x4*>(out + orow + g * 8 + hl * 4) = pk;
#pragma unroll
    for (int e = 0; e < 4; ++e) pk[e] = f2b(oB[g * 4 + e] * inv);
    *reinterpret_cast<u16x4*>(out + orow + 32 + g * 8 + hl * 4) = pk;
  }
}

extern "C" void kernel_launch(void* const* d_in, const int* in_sizes, int n_in,
                              void* d_out, int out_size, void* d_ws, size_t ws_size,
                              hipStream_t stream) {
  (void)in_sizes; (void)n_in; (void)out_size; (void)ws_size;
  const float* x        = (const float*)d_in[0];
  const float* ns_g     = (const float*)d_in[2];
  const float* ns_b     = (const float*)d_in[3];
  const float* nt_g     = (const float*)d_in[4];
  const float* nt_b     = (const float*)d_in[5];
  const float* nf_g     = (const float*)d_in[6];
  const float* nf_b     = (const float*)d_in[7];
  const float* s_qkv_w  = (const float*)d_in[8];
  const float* s_qkv_b  = (const float*)d_in[9];
  const float* s_proj_w = (const float*)d_in[10];
  const float* s_proj_b = (const float*)d_in[11];
  const float* t_qkv_w  = (const float*)d_in[12];
  const float* t_qkv_b  = (const float*)d_in[13];
  const float* t_proj_w = (const float*)d_in[14];
  const float* t_proj_b = (const float*)d_in[15];
  const float* rpe_tab  = (const float*)d_in[16];
  const float* rpe_w    = (const float*)d_in[17];
  const float* ff_w1    = (const float*)d_in[18];
  const float* ff_b1    = (const float*)d_in[19];
  const float* ff_w2    = (const float*)d_in[20];
  const float* ff_b2    = (const float*)d_in[21];

  char* ws = (char*)d_ws;
  float* xr    = (float*)(ws);                 // 16.78 MB fp32 residual
  u16*   lnb   = (u16*)(ws + 16777216);        // 8.39 MB bf16 LN output
  u16*   big   = (u16*)(ws + 25165824);        // qkv bf16 / ffn hidden
  float* bias2 = (float*)(ws + 50331648);      // 8 KB (past qkv end; dead before ffn)
  u16*   wT    = (u16*)(ws + 58720256);        // 8.39 MB transposed bf16 weights
  u16* sqkvT  = wT;
  u16* tqkvT  = wT + 786432;
  u16* sprojT = wT + 1572864;
  u16* tprojT = wT + 1835008;
  u16* ff1T   = wT + 2097152;
  u16* ff2T   = wT + 3145728;
  u16* ao     = (u16*)d_out;     // attention output scratch
  float* outp = (float*)d_out;

  // fused prep: 6 transposes + bias + spatial LN in ONE dispatch
  prep_kernel<<<6152, 256, 0, stream>>>(
      x, ns_g, ns_b, lnb,
      s_qkv_w, sqkvT, t_qkv_w, tqkvT, s_proj_w, sprojT, t_proj_w, tprojT,
      ff_w1, ff1T, ff_w2, ff2T, rpe_tab, rpe_w, bias2);

  // --- spatial attention block ---
  gemm_kernel<0, 0, 0><<<dim3(12, 64), 256, 0, stream>>>(
      lnb, sqkvT, s_qkv_b, nullptr, big, 8192, 1536, 512);
  attn_kernel<0><<<dim3(8, 64), 256, 0, stream>>>(big, nullptr, ao);
  gemm64_kernel<0, 1, 1><<<dim3(4, 128), 256, 0, stream>>>(
      ao, sprojT, s_proj_b, x, xr, 8192, 512, 512);
  // --- temporal attention block ---
  ln_kernel<<<2048, 256, 0, stream>>>(xr, nt_g, nt_b, lnb);
  gemm_kernel<0, 0, 0><<<dim3(12, 64), 256, 0, stream>>>(
      lnb, tqkvT, t_qkv_b, nullptr, big, 8192, 1536, 512);
  attn_kernel<1><<<dim3(8, 64), 256, 0, stream>>>(big, bias2, ao);
  gemm64_kernel<0, 1, 1><<<dim3(4, 128), 256, 0, stream>>>(
      ao, tprojT, t_proj_b, xr, xr, 8192, 512, 512);
  // --- FFN block ---
  ln_kernel<<<2048, 256, 0, stream>>>(xr, nf_g, nf_b, lnb);
  gemm_kernel<1, 0, 0><<<dim3(16, 64), 256, 0, stream>>>(
      lnb, ff1T, ff_b1, nullptr, big, 8192, 2048, 512);
  gemm64_kernel<0, 1, 1><<<dim3(4, 128), 256, 0, stream>>>(
      big, ff2T, ff_b2, xr, outp, 8192, 512, 2048);
}